// Round 1
// baseline (898.012 us; speedup 1.0000x reference)
//
#include <hip/hip_runtime.h>
#include <hip/hip_bf16.h>

// Problem constants (B,C,H,W)=(16,512,48,48), K_TOP=256, eps=1e-5
#define BB   16
#define CC   512
#define NN   2304
#define KK   256
#define LNEPS 1e-5f
#define SCALE 0.04419417382415922f   // 512^-0.5

// ---------------------------------------------------------------------------
// 1) importance[b,n] = sum_c x[b,c,n]^2  (fp64 accumulate for stable ordering)
// ---------------------------------------------------------------------------
__global__ __launch_bounds__(256) void importance_kernel(const float* __restrict__ X,
                                                         float* __restrict__ imp) {
    int b = blockIdx.x / 9;                 // N = 9*256
    int n = (blockIdx.x % 9) * 256 + threadIdx.x;
    const float* xp = X + (size_t)b * CC * NN + n;
    double s = 0.0;
    #pragma unroll 8
    for (int c = 0; c < CC; ++c) {
        float v = xp[(size_t)c * NN];
        s = fma((double)v, (double)v, s);
    }
    imp[b * NN + n] = (float)s;
}

// ---------------------------------------------------------------------------
// 2) per-batch top-256 via bitonic sort of 4096 padded (val,idx) keys in LDS
//    key = mono(float)<<32 | (N-1-idx)  -> descending sort gives top_k order
//    (equal values break ties toward smaller idx, matching lax.top_k)
// ---------------------------------------------------------------------------
__global__ __launch_bounds__(1024) void topk_kernel(const float* __restrict__ imp,
                                                    int* __restrict__ idx) {
    __shared__ unsigned long long keys[4096];
    const int b = blockIdx.x, tid = threadIdx.x;
    for (int i = tid; i < 4096; i += 1024) {
        unsigned long long kv = 0ULL;
        if (i < NN) {
            unsigned u = __float_as_uint(imp[b * NN + i]);
            u = (u & 0x80000000u) ? ~u : (u | 0x80000000u);
            kv = ((unsigned long long)u << 32) | (unsigned)(NN - 1 - i);
        }
        keys[i] = kv;
    }
    __syncthreads();
    for (int k = 2; k <= 4096; k <<= 1) {
        for (int j = k >> 1; j > 0; j >>= 1) {
            for (int i = tid; i < 4096; i += 1024) {
                int l = i ^ j;
                if (l > i) {
                    unsigned long long a = keys[i], c = keys[l];
                    bool desc = ((i & k) == 0);
                    if (desc ? (a < c) : (a > c)) { keys[i] = c; keys[l] = a; }
                }
            }
            __syncthreads();
        }
    }
    if (tid < KK) idx[b * KK + tid] = NN - 1 - (int)(keys[tid] & 0xffffffffu);
}

// ---------------------------------------------------------------------------
// 3) xsel[b][c][k] = x[b][c][idx[b][k]]
// ---------------------------------------------------------------------------
__global__ __launch_bounds__(256) void gather_xsel(const float* __restrict__ X,
                                                   const int* __restrict__ idx,
                                                   float* __restrict__ Xsel) {
    size_t t = (size_t)blockIdx.x * 256 + threadIdx.x;  // B*C*K
    int k = t & 255;
    int c = (t >> 8) & 511;
    int b = (int)(t >> 17);
    Xsel[t] = X[((size_t)b * CC + c) * NN + idx[b * KK + k]];
}

// ---------------------------------------------------------------------------
// Generic fp32 tiled GEMM: Y[M][NNc] = A[M][Kd] * B(Kd x NNc)  (per batch z)
//   A row-major with contiguous reduction dim (transposed into LDS).
//   BT=false: B is [Kd][NNc] row-major. BT=true: B is [NNc][Kd] row-major.
//   YT=true : store transposed -> Y[n][m].
//   SC      : y = clip(y*scalev, -80, 80).   RES: y += R (same layout as Y).
// 64x64 block tile, 256 threads, 4x4 per thread, K-step 16.
// ---------------------------------------------------------------------------
template<bool BT, bool RES, bool SC, bool YT>
__global__ __launch_bounds__(256) void tile_gemm(
    const float* __restrict__ A, long sAb, int lda,
    const float* __restrict__ Bm, long sBb, int ldb,
    const float* __restrict__ R, long sRb,
    float* __restrict__ Y, long sYb, int ldy,
    int Kd, float scalev)
{
    __shared__ float At[16][68];   // +4 pad: transposed-store writes are 2-way (free)
    __shared__ float Bt[16][68];
    const int b  = blockIdx.z;
    const int n0 = blockIdx.x * 64;
    const int m0 = blockIdx.y * 64;
    const int tid = threadIdx.x;
    const int ti = tid >> 4, tj = tid & 15;
    const int arow = tid >> 2, akk = (tid & 3) << 2;   // transpose-load mapping
    const int bkk  = tid >> 4, bjx = (tid & 15) << 2;  // natural-load mapping
    const float* Ab = A  + (size_t)b * sAb;
    const float* Bb = Bm + (size_t)b * sBb;
    float acc[4][4] = {{0.f}};

    for (int k0 = 0; k0 < Kd; k0 += 16) {
        float4 a4 = *(const float4*)&Ab[(size_t)(m0 + arow) * lda + k0 + akk];
        At[akk + 0][arow] = a4.x; At[akk + 1][arow] = a4.y;
        At[akk + 2][arow] = a4.z; At[akk + 3][arow] = a4.w;
        if (BT) {
            float4 b4 = *(const float4*)&Bb[(size_t)(n0 + arow) * ldb + k0 + akk];
            Bt[akk + 0][arow] = b4.x; Bt[akk + 1][arow] = b4.y;
            Bt[akk + 2][arow] = b4.z; Bt[akk + 3][arow] = b4.w;
        } else {
            *(float4*)&Bt[bkk][bjx] = *(const float4*)&Bb[(size_t)(k0 + bkk) * ldb + n0 + bjx];
        }
        __syncthreads();
        #pragma unroll
        for (int kk = 0; kk < 16; ++kk) {
            const float4 av = *(const float4*)&At[kk][ti * 4];
            const float4 bv = *(const float4*)&Bt[kk][tj * 4];
            const float ar[4] = {av.x, av.y, av.z, av.w};
            const float br[4] = {bv.x, bv.y, bv.z, bv.w};
            #pragma unroll
            for (int r = 0; r < 4; ++r)
                #pragma unroll
                for (int c = 0; c < 4; ++c)
                    acc[r][c] += ar[r] * br[c];
        }
        __syncthreads();
    }

    float* Yb = Y + (size_t)b * sYb;
    if (YT) {
        #pragma unroll
        for (int c = 0; c < 4; ++c) {
            float4 o4 = make_float4(acc[0][c], acc[1][c], acc[2][c], acc[3][c]);
            *(float4*)&Yb[(size_t)(n0 + tj * 4 + c) * ldy + (m0 + ti * 4)] = o4;
        }
    } else {
        const float* Rb = RES ? (R + (size_t)b * sRb) : nullptr;
        #pragma unroll
        for (int r = 0; r < 4; ++r) {
            float4 o4 = make_float4(acc[r][0], acc[r][1], acc[r][2], acc[r][3]);
            if (SC) {
                o4.x = fminf(fmaxf(o4.x * scalev, -80.f), 80.f);
                o4.y = fminf(fmaxf(o4.y * scalev, -80.f), 80.f);
                o4.z = fminf(fmaxf(o4.z * scalev, -80.f), 80.f);
                o4.w = fminf(fmaxf(o4.w * scalev, -80.f), 80.f);
            }
            size_t off = (size_t)(m0 + ti * 4 + r) * ldy + n0 + tj * 4;
            if (RES) {
                float4 r4 = *(const float4*)&Rb[off];
                o4.x += r4.x; o4.y += r4.y; o4.z += r4.z; o4.w += r4.w;
            }
            *(float4*)&Yb[off] = o4;
        }
    }
}

// ---------------------------------------------------------------------------
// 5) LayerNorm rows in-place: Q[row][512], one wave per row
// ---------------------------------------------------------------------------
__global__ __launch_bounds__(256) void ln_rows(float* __restrict__ Q,
                                               const float* __restrict__ lnw,
                                               const float* __restrict__ lnb) {
    const int wave = threadIdx.x >> 6, lane = threadIdx.x & 63;
    const int row = blockIdx.x * 4 + wave;          // < B*K
    float* p = Q + (size_t)row * CC;
    float4 v0 = *(float4*)&p[lane * 4];
    float4 v1 = *(float4*)&p[256 + lane * 4];
    float s  = v0.x + v0.y + v0.z + v0.w + v1.x + v1.y + v1.z + v1.w;
    float s2 = v0.x*v0.x + v0.y*v0.y + v0.z*v0.z + v0.w*v0.w
             + v1.x*v1.x + v1.y*v1.y + v1.z*v1.z + v1.w*v1.w;
    #pragma unroll
    for (int m = 32; m >= 1; m >>= 1) { s += __shfl_xor(s, m); s2 += __shfl_xor(s2, m); }
    const float mean = s * (1.f / 512.f);
    const float var  = s2 * (1.f / 512.f) - mean * mean;
    const float rstd = rsqrtf(var + LNEPS);
    float4 w0 = *(const float4*)&lnw[lane * 4],        b0 = *(const float4*)&lnb[lane * 4];
    float4 w1 = *(const float4*)&lnw[256 + lane * 4],  b1 = *(const float4*)&lnb[256 + lane * 4];
    v0.x = (v0.x - mean) * rstd * w0.x + b0.x;  v0.y = (v0.y - mean) * rstd * w0.y + b0.y;
    v0.z = (v0.z - mean) * rstd * w0.z + b0.z;  v0.w = (v0.w - mean) * rstd * w0.w + b0.w;
    v1.x = (v1.x - mean) * rstd * w1.x + b1.x;  v1.y = (v1.y - mean) * rstd * w1.y + b1.y;
    v1.z = (v1.z - mean) * rstd * w1.z + b1.z;  v1.w = (v1.w - mean) * rstd * w1.w + b1.w;
    *(float4*)&p[lane * 4] = v0;
    *(float4*)&p[256 + lane * 4] = v1;
}

// ---------------------------------------------------------------------------
// 7) softmax over rows of S[row][256] in-place, one wave per row
// ---------------------------------------------------------------------------
__global__ __launch_bounds__(256) void softmax_rows(float* __restrict__ S) {
    const int wave = threadIdx.x >> 6, lane = threadIdx.x & 63;
    const int row = blockIdx.x * 4 + wave;
    float* p = S + (size_t)row * KK;
    float4 v = *(float4*)&p[lane * 4];
    float m = fmaxf(fmaxf(v.x, v.y), fmaxf(v.z, v.w));
    #pragma unroll
    for (int mk = 32; mk >= 1; mk >>= 1) m = fmaxf(m, __shfl_xor(m, mk));
    float4 e = make_float4(expf(v.x - m), expf(v.y - m), expf(v.z - m), expf(v.w - m));
    float s = e.x + e.y + e.z + e.w;
    #pragma unroll
    for (int mk = 32; mk >= 1; mk >>= 1) s += __shfl_xor(s, mk);
    const float inv = 1.f / s;
    e.x *= inv; e.y *= inv; e.z *= inv; e.w *= inv;
    *(float4*)&p[lane * 4] = e;
}

// ---------------------------------------------------------------------------
// 8) vsel[b][j][c] = V[b][c][idx[b][j]]   (one wave per (b,j))
// ---------------------------------------------------------------------------
__global__ __launch_bounds__(256) void gather_vsel(const float* __restrict__ V,
                                                   const int* __restrict__ idx,
                                                   float* __restrict__ Vsel) {
    const int wave = threadIdx.x >> 6, lane = threadIdx.x & 63;
    const int gj = blockIdx.x * 4 + wave;
    const int b = gj >> 8, j = gj & 255;
    const int n = idx[b * KK + j];
    const float* vp = V + (size_t)b * CC * NN + n;
    float* op = Vsel + (size_t)gj * CC;
    #pragma unroll
    for (int r = 0; r < 8; ++r) {
        int c = lane + 64 * r;
        op[c] = vp[(size_t)c * NN];
    }
}

// ---------------------------------------------------------------------------
// 10) scatter: V[b][c][idx[b][i]] = Att[b][i][c]
// ---------------------------------------------------------------------------
__global__ __launch_bounds__(256) void scatter_att(const float* __restrict__ Att,
                                                   const int* __restrict__ idx,
                                                   float* __restrict__ V) {
    const int wave = threadIdx.x >> 6, lane = threadIdx.x & 63;
    const int gi = blockIdx.x * 4 + wave;
    const int b = gi >> 8, i = gi & 255;
    const int n = idx[b * KK + i];
    const float* ap = Att + (size_t)gi * CC;
    float* vp = V + (size_t)b * CC * NN + n;
    #pragma unroll
    for (int r = 0; r < 8; ++r) {
        int c = lane + 64 * r;
        vp[(size_t)c * NN] = ap[c];
    }
}

// ---------------------------------------------------------------------------
extern "C" void kernel_launch(void* const* d_in, const int* in_sizes, int n_in,
                              void* d_out, int out_size, void* d_ws, size_t ws_size,
                              hipStream_t stream) {
    const float* x   = (const float*)d_in[0];
    const float* wq  = (const float*)d_in[1];
    const float* wk  = (const float*)d_in[2];
    const float* wv  = (const float*)d_in[3];
    const float* wo  = (const float*)d_in[4];
    const float* lnw = (const float*)d_in[5];
    const float* lnb = (const float*)d_in[6];
    float* out = (float*)d_out;

    // workspace layout (floats)
    float* ws   = (float*)d_ws;
    float* imp  = ws;                         // B*N           = 36864
    int*   idx  = (int*)(ws + 36864);         // B*K           = 4096
    float* xsel = ws + 36864 + 4096;          // B*C*K         = 2097152
    float* qbuf = xsel + 2097152;             // B*K*C         = 2097152
    float* kbuf = qbuf + 2097152;             // B*K*C
    float* S    = kbuf + 2097152;             // B*K*K         = 1048576
    float* vsel = S    + 1048576;             // B*K*C         = 2097152
    float* vbuf = vsel + 2097152;             // B*C*N         = 18874368
    float* att  = xsel;                       // alias: xsel dead after q/k proj

    const long sX = (long)CC * NN;            // per-batch x / v stride
    const long sQ = (long)KK * CC;            // per-batch [k][c] stride
    const long sS = (long)KK * KK;

    // 1) importance
    importance_kernel<<<dim3(BB * 9), dim3(256), 0, stream>>>(x, imp);
    // 2) top-k
    topk_kernel<<<dim3(BB), dim3(1024), 0, stream>>>(imp, idx);
    // 3) gather selected x columns
    gather_xsel<<<dim3(8192), dim3(256), 0, stream>>>(x, idx, xsel);
    // 4) q/k projections on selected columns, stored transposed as [b][k][o]
    tile_gemm<false,false,false,true><<<dim3(KK/64, CC/64, BB), dim3(256), 0, stream>>>(
        wq, 0, CC, xsel, sQ, KK, nullptr, 0, qbuf, sQ, CC, CC, 1.f);
    tile_gemm<false,false,false,true><<<dim3(KK/64, CC/64, BB), dim3(256), 0, stream>>>(
        wk, 0, CC, xsel, sQ, KK, nullptr, 0, kbuf, sQ, CC, CC, 1.f);
    // 4b) full v projection -> vbuf[b][c][n]
    tile_gemm<false,false,false,false><<<dim3(NN/64, CC/64, BB), dim3(256), 0, stream>>>(
        wv, 0, CC, x, sX, NN, nullptr, 0, vbuf, sX, NN, CC, 1.f);
    // 5) layernorm q,k rows in-place
    ln_rows<<<dim3(BB * KK / 4), dim3(256), 0, stream>>>(qbuf, lnw, lnb);
    ln_rows<<<dim3(BB * KK / 4), dim3(256), 0, stream>>>(kbuf, lnw, lnb);
    // 6) attention logits S = clip(scale * Qn Kn^T)
    tile_gemm<true,false,true,false><<<dim3(KK/64, KK/64, BB), dim3(256), 0, stream>>>(
        qbuf, sQ, CC, kbuf, sQ, CC, nullptr, 0, S, sS, KK, CC, SCALE);
    // 7) softmax rows
    softmax_rows<<<dim3(BB * KK / 4), dim3(256), 0, stream>>>(S);
    // 8) gather v at selected columns -> vsel[b][j][c]
    gather_vsel<<<dim3(BB * KK / 4), dim3(256), 0, stream>>>(vbuf, idx, vsel);
    // 9) attended = P @ vsel -> att[b][i][c]
    tile_gemm<false,false,false,false><<<dim3(CC/64, KK/64, BB), dim3(256), 0, stream>>>(
        S, sS, KK, vsel, sQ, CC, nullptr, 0, att, sQ, CC, KK, 1.f);
    // 10) scatter attended back into vbuf columns
    scatter_att<<<dim3(BB * KK / 4), dim3(256), 0, stream>>>(att, idx, vbuf);
    // 11) out = x + wo @ vbuf
    tile_gemm<false,true,false,false><<<dim3(NN/64, CC/64, BB), dim3(256), 0, stream>>>(
        wo, 0, CC, vbuf, sX, NN, x, sX, out, sX, NN, CC, 1.f);
}

// Round 7
// 568.913 us; speedup vs baseline: 1.5785x; 1.5785x over previous
//
#include <hip/hip_runtime.h>
#include <hip/hip_bf16.h>

// Problem constants (B,C,H,W)=(16,512,48,48), K_TOP=256, eps=1e-5
#define BB   16
#define CC   512
#define NN   2304
#define KK   256
#define LNEPS 1e-5f
#define SCALE 0.04419417382415922f   // 512^-0.5

typedef unsigned int  u32;
typedef unsigned short u16;
typedef __attribute__((ext_vector_type(8))) short short8;
typedef __attribute__((ext_vector_type(4))) float f32x4;

// ---------------- bf16 split helpers (RNE) ----------------
__device__ __forceinline__ u32 f2bf_u(float f) {
    u32 u = __float_as_uint(f);
    return (u + 0x7fffu + ((u >> 16) & 1u)) >> 16;
}
__device__ __forceinline__ u32 packf(float f) {
    u32 h = f2bf_u(f);
    float hf = __uint_as_float(h << 16);
    u32 l = f2bf_u(f - hf);
    return h | (l << 16);
}
__device__ __forceinline__ float unpackf(u32 p) {
    return __uint_as_float(p << 16) + __uint_as_float(p & 0xffff0000u);
}

__device__ __forceinline__ void gl16(const void* g, void* l) {
    __builtin_amdgcn_global_load_lds((const __attribute__((address_space(1))) u32*)g,
                                     (__attribute__((address_space(3))) u32*)l, 16, 0, 0);
}

// ---------------------------------------------------------------------------
// 1) importance[b,n] = sum_c x[b,c,n]^2  (fp64 accumulate for stable ordering)
// ---------------------------------------------------------------------------
__global__ __launch_bounds__(256) void importance_kernel(const float* __restrict__ X,
                                                         float* __restrict__ imp) {
    int b = blockIdx.x / 9;
    int n = (blockIdx.x % 9) * 256 + threadIdx.x;
    const float* xp = X + (size_t)b * CC * NN + n;
    double s = 0.0;
    #pragma unroll 8
    for (int c = 0; c < CC; ++c) {
        float v = xp[(size_t)c * NN];
        s = fma((double)v, (double)v, s);
    }
    imp[b * NN + n] = (float)s;
}

// ---------------------------------------------------------------------------
// 2) per-batch top-256 via bitonic sort (ties -> smaller idx, matches top_k)
// ---------------------------------------------------------------------------
__global__ __launch_bounds__(1024) void topk_kernel(const float* __restrict__ imp,
                                                    int* __restrict__ idx) {
    __shared__ unsigned long long keys[4096];
    const int b = blockIdx.x, tid = threadIdx.x;
    for (int i = tid; i < 4096; i += 1024) {
        unsigned long long kv = 0ULL;
        if (i < NN) {
            unsigned u = __float_as_uint(imp[b * NN + i]);
            u = (u & 0x80000000u) ? ~u : (u | 0x80000000u);
            kv = ((unsigned long long)u << 32) | (unsigned)(NN - 1 - i);
        }
        keys[i] = kv;
    }
    __syncthreads();
    for (int k = 2; k <= 4096; k <<= 1) {
        for (int j = k >> 1; j > 0; j >>= 1) {
            for (int i = tid; i < 4096; i += 1024) {
                int l = i ^ j;
                if (l > i) {
                    unsigned long long a = keys[i], c = keys[l];
                    bool desc = ((i & k) == 0);
                    if (desc ? (a < c) : (a > c)) { keys[i] = c; keys[l] = a; }
                }
            }
            __syncthreads();
        }
    }
    if (tid < KK) idx[b * KK + tid] = NN - 1 - (int)(keys[tid] & 0xffffffffu);
}

// ---------------------------------------------------------------------------
// 3) xsel[b][c][k] = x[b][c][idx[b][k]]  (for the fp32 q/k path)
// ---------------------------------------------------------------------------
__global__ __launch_bounds__(256) void gather_xsel(const float* __restrict__ X,
                                                   const int* __restrict__ idx,
                                                   float* __restrict__ Xsel) {
    size_t t = (size_t)blockIdx.x * 256 + threadIdx.x;
    int k = t & 255;
    int c = (t >> 8) & 511;
    int b = (int)(t >> 17);
    Xsel[t] = X[((size_t)b * CC + c) * NN + idx[b * KK + k]];
}

// ---------------------------------------------------------------------------
// 4) transpose-convert: x[b][c][n] f32 -> XT[b][n][c] u32 (bf16 hi | lo<<16)
//    64x64 tiles via padded LDS.
// ---------------------------------------------------------------------------
__global__ __launch_bounds__(256) void transpose_cvt(const float* __restrict__ X,
                                                     u32* __restrict__ XT) {
    __shared__ u32 T[64 * 65];
    const int b = blockIdx.z;
    const int n0 = blockIdx.x * 64, c0 = blockIdx.y * 64;
    const int t = threadIdx.x;
    const int cl = t >> 4, nl4 = (t & 15) * 4;
    #pragma unroll
    for (int p = 0; p < 4; ++p) {
        int c = cl + 16 * p;
        float4 v = *(const float4*)&X[((size_t)(b * CC + c0 + c)) * NN + n0 + nl4];
        T[c * 65 + nl4 + 0] = packf(v.x);
        T[c * 65 + nl4 + 1] = packf(v.y);
        T[c * 65 + nl4 + 2] = packf(v.z);
        T[c * 65 + nl4 + 3] = packf(v.w);
    }
    __syncthreads();
    const int cch = t & 15;
    #pragma unroll
    for (int q = 0; q < 4; ++q) {
        int n = (t >> 4) + 16 * q;
        uint4 o;
        o.x = T[(cch * 4 + 0) * 65 + n];
        o.y = T[(cch * 4 + 1) * 65 + n];
        o.z = T[(cch * 4 + 2) * 65 + n];
        o.w = T[(cch * 4 + 3) * 65 + n];
        *(uint4*)&XT[((size_t)b * NN + n0 + n) * CC + c0 + cch * 4] = o;
    }
}

// ---------------------------------------------------------------------------
// 5) weight convert: W[512][512] f32 -> Wh, Wl bf16-bit arrays (k-contiguous)
// ---------------------------------------------------------------------------
__global__ __launch_bounds__(256) void cvt_w(const float* __restrict__ W,
                                             u16* __restrict__ Wh, u16* __restrict__ Wl) {
    int i4 = (blockIdx.x * 256 + threadIdx.x) * 4;
    float4 v = *(const float4*)&W[i4];
    ushort4 h, l;
    h.x = (u16)f2bf_u(v.x); l.x = (u16)f2bf_u(v.x - __uint_as_float((u32)h.x << 16));
    h.y = (u16)f2bf_u(v.y); l.y = (u16)f2bf_u(v.y - __uint_as_float((u32)h.y << 16));
    h.z = (u16)f2bf_u(v.z); l.z = (u16)f2bf_u(v.z - __uint_as_float((u32)h.z << 16));
    h.w = (u16)f2bf_u(v.w); l.w = (u16)f2bf_u(v.w - __uint_as_float((u32)h.w << 16));
    *(ushort4*)&Wh[i4] = h;
    *(ushort4*)&Wl[i4] = l;
}

// ---------------------------------------------------------------------------
// 6) Split-bf16 MFMA GEMM: D[c][n] = sum_k W[c][k] * B[n][k]   (K=512)
//    A: Wh/Wl bf16 rows (k-contig). B: packed u32 rows (k-contig), per-batch.
//    EPI=0: Y = packed u32 [n][c] (vbufT).  EPI=1: Y = f32 [c][n] + residual.
//    128x128 tile, BK=32, 4 waves, global_load_lds w/ XOR-chunk pre-swizzle.
// ---------------------------------------------------------------------------
template<int EPI>
__global__ __launch_bounds__(256) void mfma_gemm(
    const u16* __restrict__ Ah, const u16* __restrict__ Al,
    const u32* __restrict__ Bpk, const float* __restrict__ Xres,
    void* __restrict__ Yv)
{
    __shared__ u16 sAh[128 * 32];
    __shared__ u16 sAl[128 * 32];
    __shared__ u32 sB[128 * 32];
    const int b = blockIdx.z;
    const int n0 = blockIdx.x * 128;
    const int c0 = blockIdx.y * 128;
    const int t = threadIdx.x;
    const int wid = t >> 6, lane = t & 63;
    const int mw = (wid >> 1) * 64, nw = (wid & 1) * 64;
    const int lm = lane & 15, lk = lane >> 4;
    const u32* Bb = Bpk + (size_t)b * NN * CC;

    f32x4 acc[4][4] = {};

    for (int k0 = 0; k0 < 512; k0 += 32) {
        #pragma unroll
        for (int i = 0; i < 2; ++i) {          // A tiles: 2x 8KB
            int e = t + 256 * i, r = e >> 2, ch = e & 3;
            int gch = ch ^ (r & 3);            // pre-swizzled source chunk
            gl16(&Ah[(size_t)(c0 + r) * 512 + k0 + gch * 8], &sAh[e * 8]);
            gl16(&Al[(size_t)(c0 + r) * 512 + k0 + gch * 8], &sAl[e * 8]);
        }
        #pragma unroll
        for (int i = 0; i < 4; ++i) {          // B tile: 16KB
            int e = t + 256 * i, r = e >> 3, ch = e & 7;
            int gch = ch ^ (r & 7);
            gl16(&Bb[(size_t)(n0 + r) * 512 + k0 + gch * 4], &sB[e * 4]);
        }
        __syncthreads();

        short8 ah[4], al[4], bh[4], bl[4];
        #pragma unroll
        for (int i = 0; i < 4; ++i) {
            int m = mw + 16 * i + lm;
            int ach = lk ^ (m & 3);            // swizzled read
            ah[i] = *(const short8*)&sAh[m * 32 + ach * 8];
            al[i] = *(const short8*)&sAl[m * 32 + ach * 8];
        }
        #pragma unroll
        for (int j = 0; j < 4; ++j) {
            int n = nw + 16 * j + lm;
            const u32* prow = &sB[n * 32];
            int ca = (2 * lk) ^ (n & 7);
            int cb = (2 * lk + 1) ^ (n & 7);
            uint4 u0 = *(const uint4*)&prow[ca * 4];   // k 0..3 (hi|lo packed)
            uint4 u1 = *(const uint4*)&prow[cb * 4];   // k 4..7
            union { u32 u[4]; short8 s; } H, L;
            H.u[0] = __builtin_amdgcn_perm(u0.y, u0.x, 0x05040100u);
            H.u[1] = __builtin_amdgcn_perm(u0.w, u0.z, 0x05040100u);
            H.u[2] = __builtin_amdgcn_perm(u1.y, u1.x, 0x05040100u);
            H.u[3] = __builtin_amdgcn_perm(u1.w, u1.z, 0x05040100u);
            L.u[0] = __builtin_amdgcn_perm(u0.y, u0.x, 0x07060302u);
            L.u[1] = __builtin_amdgcn_perm(u0.w, u0.z, 0x07060302u);
            L.u[2] = __builtin_amdgcn_perm(u1.y, u1.x, 0x07060302u);
            L.u[3] = __builtin_amdgcn_perm(u1.w, u1.z, 0x07060302u);
            bh[j] = H.s; bl[j] = L.s;
        }
        #pragma unroll
        for (int i = 0; i < 4; ++i)
            #pragma unroll
            for (int j = 0; j < 4; ++j) {
                acc[i][j] = __builtin_amdgcn_mfma_f32_16x16x32_bf16(ah[i], bh[j], acc[i][j], 0, 0, 0);
                acc[i][j] = __builtin_amdgcn_mfma_f32_16x16x32_bf16(ah[i], bl[j], acc[i][j], 0, 0, 0);
                acc[i][j] = __builtin_amdgcn_mfma_f32_16x16x32_bf16(al[i], bh[j], acc[i][j], 0, 0, 0);
            }
        __syncthreads();
    }

    if (EPI == 0) {
        u32* Y = (u32*)Yv + (size_t)b * NN * CC;
        #pragma unroll
        for (int i = 0; i < 4; ++i)
            #pragma unroll
            for (int j = 0; j < 4; ++j) {
                uint4 o;
                o.x = packf(acc[i][j][0]);
                o.y = packf(acc[i][j][1]);
                o.z = packf(acc[i][j][2]);
                o.w = packf(acc[i][j][3]);
                *(uint4*)&Y[(size_t)(n0 + nw + 16 * j + lm) * CC + c0 + mw + 16 * i + 4 * lk] = o;
            }
    } else {
        float* Y = (float*)Yv + (size_t)b * CC * NN;
        const float* Xb = Xres + (size_t)b * CC * NN;
        #pragma unroll
        for (int i = 0; i < 4; ++i)
            #pragma unroll
            for (int r = 0; r < 4; ++r) {
                size_t roff = (size_t)(c0 + mw + 16 * i + 4 * lk + r) * NN;
                #pragma unroll
                for (int j = 0; j < 4; ++j) {
                    size_t off = roff + n0 + nw + 16 * j + lm;
                    Y[off] = acc[i][j][r] + Xb[off];
                }
            }
    }
}

// ---------------------------------------------------------------------------
// fp32 tiled GEMM (unchanged, for q/k proj, S, PV)
// ---------------------------------------------------------------------------
template<bool BT, bool RES, bool SC, bool YT>
__global__ __launch_bounds__(256) void tile_gemm(
    const float* __restrict__ A, long sAb, int lda,
    const float* __restrict__ Bm, long sBb, int ldb,
    const float* __restrict__ R, long sRb,
    float* __restrict__ Y, long sYb, int ldy,
    int Kd, float scalev)
{
    __shared__ float At[16][68];
    __shared__ float Bt[16][68];
    const int b  = blockIdx.z;
    const int n0 = blockIdx.x * 64;
    const int m0 = blockIdx.y * 64;
    const int tid = threadIdx.x;
    const int ti = tid >> 4, tj = tid & 15;
    const int arow = tid >> 2, akk = (tid & 3) << 2;
    const int bkk  = tid >> 4, bjx = (tid & 15) << 2;
    const float* Ab = A  + (size_t)b * sAb;
    const float* Bb = Bm + (size_t)b * sBb;
    float acc[4][4] = {{0.f}};

    for (int k0 = 0; k0 < Kd; k0 += 16) {
        float4 a4 = *(const float4*)&Ab[(size_t)(m0 + arow) * lda + k0 + akk];
        At[akk + 0][arow] = a4.x; At[akk + 1][arow] = a4.y;
        At[akk + 2][arow] = a4.z; At[akk + 3][arow] = a4.w;
        if (BT) {
            float4 b4 = *(const float4*)&Bb[(size_t)(n0 + arow) * ldb + k0 + akk];
            Bt[akk + 0][arow] = b4.x; Bt[akk + 1][arow] = b4.y;
            Bt[akk + 2][arow] = b4.z; Bt[akk + 3][arow] = b4.w;
        } else {
            *(float4*)&Bt[bkk][bjx] = *(const float4*)&Bb[(size_t)(k0 + bkk) * ldb + n0 + bjx];
        }
        __syncthreads();
        #pragma unroll
        for (int kk = 0; kk < 16; ++kk) {
            const float4 av = *(const float4*)&At[kk][ti * 4];
            const float4 bv = *(const float4*)&Bt[kk][tj * 4];
            const float ar[4] = {av.x, av.y, av.z, av.w};
            const float br[4] = {bv.x, bv.y, bv.z, bv.w};
            #pragma unroll
            for (int r = 0; r < 4; ++r)
                #pragma unroll
                for (int c = 0; c < 4; ++c)
                    acc[r][c] += ar[r] * br[c];
        }
        __syncthreads();
    }

    float* Yb = Y + (size_t)b * sYb;
    if (YT) {
        #pragma unroll
        for (int c = 0; c < 4; ++c) {
            float4 o4 = make_float4(acc[0][c], acc[1][c], acc[2][c], acc[3][c]);
            *(float4*)&Yb[(size_t)(n0 + tj * 4 + c) * ldy + (m0 + ti * 4)] = o4;
        }
    } else {
        const float* Rb = RES ? (R + (size_t)b * sRb) : nullptr;
        #pragma unroll
        for (int r = 0; r < 4; ++r) {
            float4 o4 = make_float4(acc[r][0], acc[r][1], acc[r][2], acc[r][3]);
            if (SC) {
                o4.x = fminf(fmaxf(o4.x * scalev, -80.f), 80.f);
                o4.y = fminf(fmaxf(o4.y * scalev, -80.f), 80.f);
                o4.z = fminf(fmaxf(o4.z * scalev, -80.f), 80.f);
                o4.w = fminf(fmaxf(o4.w * scalev, -80.f), 80.f);
            }
            size_t off = (size_t)(m0 + ti * 4 + r) * ldy + n0 + tj * 4;
            if (RES) {
                float4 r4 = *(const float4*)&Rb[off];
                o4.x += r4.x; o4.y += r4.y; o4.z += r4.z; o4.w += r4.w;
            }
            *(float4*)&Yb[off] = o4;
        }
    }
}

// ---------------------------------------------------------------------------
// LayerNorm rows in-place (one wave per row of 512)
// ---------------------------------------------------------------------------
__global__ __launch_bounds__(256) void ln_rows(float* __restrict__ Q,
                                               const float* __restrict__ lnw,
                                               const float* __restrict__ lnb) {
    const int wave = threadIdx.x >> 6, lane = threadIdx.x & 63;
    const int row = blockIdx.x * 4 + wave;
    float* p = Q + (size_t)row * CC;
    float4 v0 = *(float4*)&p[lane * 4];
    float4 v1 = *(float4*)&p[256 + lane * 4];
    float s  = v0.x + v0.y + v0.z + v0.w + v1.x + v1.y + v1.z + v1.w;
    float s2 = v0.x*v0.x + v0.y*v0.y + v0.z*v0.z + v0.w*v0.w
             + v1.x*v1.x + v1.y*v1.y + v1.z*v1.z + v1.w*v1.w;
    #pragma unroll
    for (int m = 32; m >= 1; m >>= 1) { s += __shfl_xor(s, m); s2 += __shfl_xor(s2, m); }
    const float mean = s * (1.f / 512.f);
    const float var  = s2 * (1.f / 512.f) - mean * mean;
    const float rstd = rsqrtf(var + LNEPS);
    float4 w0 = *(const float4*)&lnw[lane * 4],        b0 = *(const float4*)&lnb[lane * 4];
    float4 w1 = *(const float4*)&lnw[256 + lane * 4],  b1 = *(const float4*)&lnb[256 + lane * 4];
    v0.x = (v0.x - mean) * rstd * w0.x + b0.x;  v0.y = (v0.y - mean) * rstd * w0.y + b0.y;
    v0.z = (v0.z - mean) * rstd * w0.z + b0.z;  v0.w = (v0.w - mean) * rstd * w0.w + b0.w;
    v1.x = (v1.x - mean) * rstd * w1.x + b1.x;  v1.y = (v1.y - mean) * rstd * w1.y + b1.y;
    v1.z = (v1.z - mean) * rstd * w1.z + b1.z;  v1.w = (v1.w - mean) * rstd * w1.w + b1.w;
    *(float4*)&p[lane * 4] = v0;
    *(float4*)&p[256 + lane * 4] = v1;
}

// ---------------------------------------------------------------------------
// softmax over rows of S[row][256] in-place (one wave per row)
// ---------------------------------------------------------------------------
__global__ __launch_bounds__(256) void softmax_rows(float* __restrict__ S) {
    const int wave = threadIdx.x >> 6, lane = threadIdx.x & 63;
    const int row = blockIdx.x * 4 + wave;
    float* p = S + (size_t)row * KK;
    float4 v = *(float4*)&p[lane * 4];
    float m = fmaxf(fmaxf(v.x, v.y), fmaxf(v.z, v.w));
    #pragma unroll
    for (int mk = 32; mk >= 1; mk >>= 1) m = fmaxf(m, __shfl_xor(m, mk));
    float4 e = make_float4(expf(v.x - m), expf(v.y - m), expf(v.z - m), expf(v.w - m));
    float s = e.x + e.y + e.z + e.w;
    #pragma unroll
    for (int mk = 32; mk >= 1; mk >>= 1) s += __shfl_xor(s, mk);
    const float inv = 1.f / s;
    e.x *= inv; e.y *= inv; e.z *= inv; e.w *= inv;
    *(float4*)&p[lane * 4] = e;
}

// ---------------------------------------------------------------------------
// gather: vsel[b*K+j][c] f32 = unpack(vbufT[b][idx][c])  (contiguous rows)
// ---------------------------------------------------------------------------
__global__ __launch_bounds__(256) void gather_vsel(const u32* __restrict__ VT,
                                                   const int* __restrict__ idx,
                                                   float* __restrict__ Vsel) {
    const int wave = threadIdx.x >> 6, lane = threadIdx.x & 63;
    const int gj = blockIdx.x * 4 + wave;
    const int b = gj >> 8, j = gj & 255;
    const int n = idx[b * KK + j];
    const u32* vp = VT + ((size_t)b * NN + n) * CC;
    float* op = Vsel + (size_t)gj * CC;
    uint4 ua = *(const uint4*)&vp[lane * 8];
    uint4 ub = *(const uint4*)&vp[lane * 8 + 4];
    float4 fa = make_float4(unpackf(ua.x), unpackf(ua.y), unpackf(ua.z), unpackf(ua.w));
    float4 fb = make_float4(unpackf(ub.x), unpackf(ub.y), unpackf(ub.z), unpackf(ub.w));
    *(float4*)&op[lane * 8] = fa;
    *(float4*)&op[lane * 8 + 4] = fb;
}

// ---------------------------------------------------------------------------
// scatter: vbufT[b][idx[i]][c] = pack(att[b*K+i][c])  (contiguous rows)
// ---------------------------------------------------------------------------
__global__ __launch_bounds__(256) void scatter_att(const float* __restrict__ Att,
                                                   const int* __restrict__ idx,
                                                   u32* __restrict__ VT) {
    const int wave = threadIdx.x >> 6, lane = threadIdx.x & 63;
    const int gi = blockIdx.x * 4 + wave;
    const int b = gi >> 8, i = gi & 255;
    const int n = idx[b * KK + i];
    const float* ap = Att + (size_t)gi * CC;
    u32* vp = VT + ((size_t)b * NN + n) * CC;
    float4 fa = *(const float4*)&ap[lane * 8];
    float4 fb = *(const float4*)&ap[lane * 8 + 4];
    uint4 ua, ub;
    ua.x = packf(fa.x); ua.y = packf(fa.y); ua.z = packf(fa.z); ua.w = packf(fa.w);
    ub.x = packf(fb.x); ub.y = packf(fb.y); ub.z = packf(fb.z); ub.w = packf(fb.w);
    *(uint4*)&vp[lane * 8] = ua;
    *(uint4*)&vp[lane * 8 + 4] = ub;
}

// ---------------------------------------------------------------------------
extern "C" void kernel_launch(void* const* d_in, const int* in_sizes, int n_in,
                              void* d_out, int out_size, void* d_ws, size_t ws_size,
                              hipStream_t stream) {
    const float* x   = (const float*)d_in[0];
    const float* wq  = (const float*)d_in[1];
    const float* wk  = (const float*)d_in[2];
    const float* wv  = (const float*)d_in[3];
    const float* wo  = (const float*)d_in[4];
    const float* lnw = (const float*)d_in[5];
    const float* lnb = (const float*)d_in[6];
    float* out = (float*)d_out;

    // workspace layout (bytes); total 113,262,592 <= proven round-1 usage
    char* w = (char*)d_ws;
    int*   idx  = (int*)w;                              // 16 KB
    float* xsel = (float*)(w + 16384);                  // 8 MB (also imp, att)
    float* imp  = xsel;
    float* att  = xsel;
    float* qbuf = (float*)(w + 8404992);                // 8 MB (Wv h/l first)
    float* kbuf = (float*)(w + 16793600);               // 8 MB (Wo h/l later)
    float* S    = (float*)(w + 25182208);               // 4 MB
    float* vsel = (float*)(w + 29376512);               // 8 MB
    u32*   vbufT= (u32*)(w + 37765120);                 // 75.5 MB packed [b][n][c]
    u16* WvH = (u16*)qbuf;  u16* WvL = WvH + 262144;
    u16* WoH = (u16*)kbuf;  u16* WoL = WoH + 262144;
    u32* XT  = (u32*)d_out;                             // x^T packed, scratch in d_out

    const long sX = (long)CC * NN;
    const long sQ = (long)KK * CC;
    const long sS = (long)KK * KK;

    importance_kernel<<<dim3(BB * 9), dim3(256), 0, stream>>>(x, imp);
    topk_kernel<<<dim3(BB), dim3(1024), 0, stream>>>(imp, idx);

    cvt_w<<<dim3(256), dim3(256), 0, stream>>>(wv, WvH, WvL);
    transpose_cvt<<<dim3(NN / 64, CC / 64, BB), dim3(256), 0, stream>>>(x, XT);
    // V-projection: vbufT[n][c] = pack( (wv @ x)^T )
    mfma_gemm<0><<<dim3(NN / 128, CC / 128, BB), dim3(256), 0, stream>>>(
        WvH, WvL, XT, nullptr, (void*)vbufT);

    gather_xsel<<<dim3(8192), dim3(256), 0, stream>>>(x, idx, xsel);
    tile_gemm<false,false,false,true><<<dim3(KK/64, CC/64, BB), dim3(256), 0, stream>>>(
        wq, 0, CC, xsel, sQ, KK, nullptr, 0, qbuf, sQ, CC, CC, 1.f);
    tile_gemm<false,false,false,true><<<dim3(KK/64, CC/64, BB), dim3(256), 0, stream>>>(
        wk, 0, CC, xsel, sQ, KK, nullptr, 0, kbuf, sQ, CC, CC, 1.f);
    ln_rows<<<dim3(BB * KK / 4), dim3(256), 0, stream>>>(qbuf, lnw, lnb);
    ln_rows<<<dim3(BB * KK / 4), dim3(256), 0, stream>>>(kbuf, lnw, lnb);
    tile_gemm<true,false,true,false><<<dim3(KK/64, KK/64, BB), dim3(256), 0, stream>>>(
        qbuf, sQ, CC, kbuf, sQ, CC, nullptr, 0, S, sS, KK, CC, SCALE);
    softmax_rows<<<dim3(BB * KK / 4), dim3(256), 0, stream>>>(S);

    gather_vsel<<<dim3(BB * KK / 4), dim3(256), 0, stream>>>(vbufT, idx, vsel);
    tile_gemm<false,false,false,false><<<dim3(CC/64, KK/64, BB), dim3(256), 0, stream>>>(
        S, sS, KK, vsel, sQ, CC, nullptr, 0, att, sQ, CC, KK, 1.f);
    scatter_att<<<dim3(BB * KK / 4), dim3(256), 0, stream>>>(att, idx, vbufT);

    cvt_w<<<dim3(256), dim3(256), 0, stream>>>(wo, WoH, WoL);
    // O-projection: out[c][n] = x + wo @ vbuf   (B = vbufT rows, k-contig)
    mfma_gemm<1><<<dim3(NN / 128, CC / 128, BB), dim3(256), 0, stream>>>(
        WoH, WoL, vbufT, x, (void*)out);
}

// Round 8
// 531.268 us; speedup vs baseline: 1.6903x; 1.0709x over previous
//
#include <hip/hip_runtime.h>
#include <hip/hip_bf16.h>

// Problem constants (B,C,H,W)=(16,512,48,48), K_TOP=256, eps=1e-5
#define BB   16
#define CC   512
#define NN   2304
#define KK   256
#define LNEPS 1e-5f
#define SCALE 0.04419417382415922f   // 512^-0.5

typedef unsigned int  u32;
typedef unsigned short u16;
typedef __attribute__((ext_vector_type(8))) short short8;
typedef __attribute__((ext_vector_type(4))) float f32x4;

// ---------------- bf16 split helpers (RNE) ----------------
__device__ __forceinline__ u32 f2bf_u(float f) {
    u32 u = __float_as_uint(f);
    return (u + 0x7fffu + ((u >> 16) & 1u)) >> 16;
}
__device__ __forceinline__ u32 packf(float f) {
    u32 h = f2bf_u(f);
    float hf = __uint_as_float(h << 16);
    u32 l = f2bf_u(f - hf);
    return h | (l << 16);
}
__device__ __forceinline__ float unpackf(u32 p) {
    return __uint_as_float(p << 16) + __uint_as_float(p & 0xffff0000u);
}

__device__ __forceinline__ void gl16(const void* g, void* l) {
    __builtin_amdgcn_global_load_lds((const __attribute__((address_space(1))) u32*)g,
                                     (__attribute__((address_space(3))) u32*)l, 16, 0, 0);
}

// ---------------------------------------------------------------------------
// 1) importance[b,n] = sum_c x[b,c,n]^2  (fp64 accumulate for stable ordering)
// ---------------------------------------------------------------------------
__global__ __launch_bounds__(256) void importance_kernel(const float* __restrict__ X,
                                                         float* __restrict__ imp) {
    int b = blockIdx.x / 9;
    int n = (blockIdx.x % 9) * 256 + threadIdx.x;
    const float* xp = X + (size_t)b * CC * NN + n;
    double s = 0.0;
    #pragma unroll 8
    for (int c = 0; c < CC; ++c) {
        float v = xp[(size_t)c * NN];
        s = fma((double)v, (double)v, s);
    }
    imp[b * NN + n] = (float)s;
}

// ---------------------------------------------------------------------------
// 2) per-batch top-256 via bitonic sort (ties -> smaller idx, matches top_k)
// ---------------------------------------------------------------------------
__global__ __launch_bounds__(1024) void topk_kernel(const float* __restrict__ imp,
                                                    int* __restrict__ idx) {
    __shared__ unsigned long long keys[4096];
    const int b = blockIdx.x, tid = threadIdx.x;
    for (int i = tid; i < 4096; i += 1024) {
        unsigned long long kv = 0ULL;
        if (i < NN) {
            unsigned u = __float_as_uint(imp[b * NN + i]);
            u = (u & 0x80000000u) ? ~u : (u | 0x80000000u);
            kv = ((unsigned long long)u << 32) | (unsigned)(NN - 1 - i);
        }
        keys[i] = kv;
    }
    __syncthreads();
    for (int k = 2; k <= 4096; k <<= 1) {
        for (int j = k >> 1; j > 0; j >>= 1) {
            for (int i = tid; i < 4096; i += 1024) {
                int l = i ^ j;
                if (l > i) {
                    unsigned long long a = keys[i], c = keys[l];
                    bool desc = ((i & k) == 0);
                    if (desc ? (a < c) : (a > c)) { keys[i] = c; keys[l] = a; }
                }
            }
            __syncthreads();
        }
    }
    if (tid < KK) idx[b * KK + tid] = NN - 1 - (int)(keys[tid] & 0xffffffffu);
}

// ---------------------------------------------------------------------------
// 3) transpose-convert: x[b][c][n] f32 -> XT[b][n][c] u32 (bf16 hi | lo<<16)
// ---------------------------------------------------------------------------
__global__ __launch_bounds__(256) void transpose_cvt(const float* __restrict__ X,
                                                     u32* __restrict__ XT) {
    __shared__ u32 T[64 * 65];
    const int b = blockIdx.z;
    const int n0 = blockIdx.x * 64, c0 = blockIdx.y * 64;
    const int t = threadIdx.x;
    const int cl = t >> 4, nl4 = (t & 15) * 4;
    #pragma unroll
    for (int p = 0; p < 4; ++p) {
        int c = cl + 16 * p;
        float4 v = *(const float4*)&X[((size_t)(b * CC + c0 + c)) * NN + n0 + nl4];
        T[c * 65 + nl4 + 0] = packf(v.x);
        T[c * 65 + nl4 + 1] = packf(v.y);
        T[c * 65 + nl4 + 2] = packf(v.z);
        T[c * 65 + nl4 + 3] = packf(v.w);
    }
    __syncthreads();
    const int cch = t & 15;
    #pragma unroll
    for (int q = 0; q < 4; ++q) {
        int n = (t >> 4) + 16 * q;
        uint4 o;
        o.x = T[(cch * 4 + 0) * 65 + n];
        o.y = T[(cch * 4 + 1) * 65 + n];
        o.z = T[(cch * 4 + 2) * 65 + n];
        o.w = T[(cch * 4 + 3) * 65 + n];
        *(uint4*)&XT[((size_t)b * NN + n0 + n) * CC + c0 + cch * 4] = o;
    }
}

// ---------------------------------------------------------------------------
// 4) weight convert: W[512][512] f32 -> Wh, Wl bf16-bit arrays (k-contiguous)
// ---------------------------------------------------------------------------
__global__ __launch_bounds__(256) void cvt_w(const float* __restrict__ W,
                                             u16* __restrict__ Wh, u16* __restrict__ Wl) {
    int i4 = (blockIdx.x * 256 + threadIdx.x) * 4;
    float4 v = *(const float4*)&W[i4];
    ushort4 h, l;
    h.x = (u16)f2bf_u(v.x); l.x = (u16)f2bf_u(v.x - __uint_as_float((u32)h.x << 16));
    h.y = (u16)f2bf_u(v.y); l.y = (u16)f2bf_u(v.y - __uint_as_float((u32)h.y << 16));
    h.z = (u16)f2bf_u(v.z); l.z = (u16)f2bf_u(v.z - __uint_as_float((u32)h.z << 16));
    h.w = (u16)f2bf_u(v.w); l.w = (u16)f2bf_u(v.w - __uint_as_float((u32)h.w << 16));
    *(ushort4*)&Wh[i4] = h;
    *(ushort4*)&Wl[i4] = l;
}

// ---------------------------------------------------------------------------
// 5) Split-bf16 MFMA GEMM: D[c][n] = sum_k W[c][k] * B[n][k]   (K=512)
//    1D grid, XCD-bijective swizzle: the 4 c-blocks of each (n,b) pair get
//    ids differing by 8 -> same XCD -> B slab served from L2 (4x less HBM).
//    rowidx != nullptr: B row n is gathered as rowidx[b*KK+n] (q/k path).
//    EPI=0: Y packed u32 [n][c].  EPI=1: Y f32 [c][n] + residual.
// ---------------------------------------------------------------------------
template<int EPI>
__global__ __launch_bounds__(256) void mfma_gemm(
    const u16* __restrict__ Ah, const u16* __restrict__ Al,
    const u32* __restrict__ Bpk, long sBb, int nbN,
    const int* __restrict__ rowidx,
    const float* __restrict__ Xres,
    void* __restrict__ Yv, long sYb)
{
    __shared__ u16 sAh[128 * 32];
    __shared__ u16 sAl[128 * 32];
    __shared__ u32 sB[128 * 32];
    // swizzle: lin = xcd + 8*slot + 32*grp ; pair p = grp*8 + xcd ; c_blk = slot
    const int lin = blockIdx.x;
    const int xcd = lin & 7, slot = (lin >> 3) & 3, grp = lin >> 5;
    const int p = grp * 8 + xcd;
    const int b = p / nbN, nb = p - b * nbN;
    const int n0 = nb * 128;
    const int c0 = slot * 128;
    const int t = threadIdx.x;
    const int wid = t >> 6, lane = t & 63;
    const int mw = (wid >> 1) * 64, nw = (wid & 1) * 64;
    const int lm = lane & 15, lk = lane >> 4;
    const u32* Bb = Bpk + (size_t)b * sBb;

    // hoist the 4 B-row base offsets (gathered for q/k path)
    size_t brow[4];
    #pragma unroll
    for (int i = 0; i < 4; ++i) {
        int r = (t >> 3) + 32 * i;
        int gr = rowidx ? rowidx[b * KK + n0 + r] : (n0 + r);
        brow[i] = (size_t)gr * CC;
    }

    f32x4 acc[4][4] = {};

    for (int k0 = 0; k0 < 512; k0 += 32) {
        #pragma unroll
        for (int i = 0; i < 2; ++i) {          // A tiles: 2x 8KB
            int e = t + 256 * i, r = e >> 2, ch = e & 3;
            int gch = ch ^ (r & 3);            // pre-swizzled source chunk
            gl16(&Ah[(size_t)(c0 + r) * 512 + k0 + gch * 8], &sAh[e * 8]);
            gl16(&Al[(size_t)(c0 + r) * 512 + k0 + gch * 8], &sAl[e * 8]);
        }
        #pragma unroll
        for (int i = 0; i < 4; ++i) {          // B tile: 16KB
            int e = t + 256 * i, ch = e & 7;
            int r = (t >> 3) + 32 * i;         // LDS row
            int gch = ch ^ (r & 7);
            gl16(&Bb[brow[i] + k0 + gch * 4], &sB[e * 4]);
        }
        __syncthreads();

        short8 ah[4], al[4], bh[4], bl[4];
        #pragma unroll
        for (int i = 0; i < 4; ++i) {
            int m = mw + 16 * i + lm;
            int ach = lk ^ (m & 3);            // swizzled read
            ah[i] = *(const short8*)&sAh[m * 32 + ach * 8];
            al[i] = *(const short8*)&sAl[m * 32 + ach * 8];
        }
        #pragma unroll
        for (int j = 0; j < 4; ++j) {
            int n = nw + 16 * j + lm;
            const u32* prow = &sB[n * 32];
            int ca = (2 * lk) ^ (n & 7);
            int cb = (2 * lk + 1) ^ (n & 7);
            uint4 u0 = *(const uint4*)&prow[ca * 4];   // k 0..3 (hi|lo packed)
            uint4 u1 = *(const uint4*)&prow[cb * 4];   // k 4..7
            union { u32 u[4]; short8 s; } H, L;
            H.u[0] = __builtin_amdgcn_perm(u0.y, u0.x, 0x05040100u);
            H.u[1] = __builtin_amdgcn_perm(u0.w, u0.z, 0x05040100u);
            H.u[2] = __builtin_amdgcn_perm(u1.y, u1.x, 0x05040100u);
            H.u[3] = __builtin_amdgcn_perm(u1.w, u1.z, 0x05040100u);
            L.u[0] = __builtin_amdgcn_perm(u0.y, u0.x, 0x07060302u);
            L.u[1] = __builtin_amdgcn_perm(u0.w, u0.z, 0x07060302u);
            L.u[2] = __builtin_amdgcn_perm(u1.y, u1.x, 0x07060302u);
            L.u[3] = __builtin_amdgcn_perm(u1.w, u1.z, 0x07060302u);
            bh[j] = H.s; bl[j] = L.s;
        }
        #pragma unroll
        for (int i = 0; i < 4; ++i)
            #pragma unroll
            for (int j = 0; j < 4; ++j) {
                acc[i][j] = __builtin_amdgcn_mfma_f32_16x16x32_bf16(ah[i], bh[j], acc[i][j], 0, 0, 0);
                acc[i][j] = __builtin_amdgcn_mfma_f32_16x16x32_bf16(ah[i], bl[j], acc[i][j], 0, 0, 0);
                acc[i][j] = __builtin_amdgcn_mfma_f32_16x16x32_bf16(al[i], bh[j], acc[i][j], 0, 0, 0);
            }
        __syncthreads();
    }

    if (EPI == 0) {
        u32* Y = (u32*)Yv + (size_t)b * sYb;
        #pragma unroll
        for (int i = 0; i < 4; ++i)
            #pragma unroll
            for (int j = 0; j < 4; ++j) {
                uint4 o;
                o.x = packf(acc[i][j][0]);
                o.y = packf(acc[i][j][1]);
                o.z = packf(acc[i][j][2]);
                o.w = packf(acc[i][j][3]);
                *(uint4*)&Y[(size_t)(n0 + nw + 16 * j + lm) * CC + c0 + mw + 16 * i + 4 * lk] = o;
            }
    } else {
        float* Y = (float*)Yv + (size_t)b * sYb;
        const float* Xb = Xres + (size_t)b * sYb;
        #pragma unroll
        for (int i = 0; i < 4; ++i)
            #pragma unroll
            for (int r = 0; r < 4; ++r) {
                size_t roff = (size_t)(c0 + mw + 16 * i + 4 * lk + r) * NN;
                #pragma unroll
                for (int j = 0; j < 4; ++j) {
                    size_t off = roff + n0 + nw + 16 * j + lm;
                    Y[off] = acc[i][j][r] + Xb[off];
                }
            }
    }
}

// ---------------------------------------------------------------------------
// fp32 tiled GEMM (for S and PV)
// ---------------------------------------------------------------------------
template<bool BT, bool RES, bool SC, bool YT>
__global__ __launch_bounds__(256) void tile_gemm(
    const float* __restrict__ A, long sAb, int lda,
    const float* __restrict__ Bm, long sBb, int ldb,
    const float* __restrict__ R, long sRb,
    float* __restrict__ Y, long sYb, int ldy,
    int Kd, float scalev)
{
    __shared__ float At[16][68];
    __shared__ float Bt[16][68];
    const int b  = blockIdx.z;
    const int n0 = blockIdx.x * 64;
    const int m0 = blockIdx.y * 64;
    const int tid = threadIdx.x;
    const int ti = tid >> 4, tj = tid & 15;
    const int arow = tid >> 2, akk = (tid & 3) << 2;
    const int bkk  = tid >> 4, bjx = (tid & 15) << 2;
    const float* Ab = A  + (size_t)b * sAb;
    const float* Bb = Bm + (size_t)b * sBb;
    float acc[4][4] = {{0.f}};

    for (int k0 = 0; k0 < Kd; k0 += 16) {
        float4 a4 = *(const float4*)&Ab[(size_t)(m0 + arow) * lda + k0 + akk];
        At[akk + 0][arow] = a4.x; At[akk + 1][arow] = a4.y;
        At[akk + 2][arow] = a4.z; At[akk + 3][arow] = a4.w;
        if (BT) {
            float4 b4 = *(const float4*)&Bb[(size_t)(n0 + arow) * ldb + k0 + akk];
            Bt[akk + 0][arow] = b4.x; Bt[akk + 1][arow] = b4.y;
            Bt[akk + 2][arow] = b4.z; Bt[akk + 3][arow] = b4.w;
        } else {
            *(float4*)&Bt[bkk][bjx] = *(const float4*)&Bb[(size_t)(k0 + bkk) * ldb + n0 + bjx];
        }
        __syncthreads();
        #pragma unroll
        for (int kk = 0; kk < 16; ++kk) {
            const float4 av = *(const float4*)&At[kk][ti * 4];
            const float4 bv = *(const float4*)&Bt[kk][tj * 4];
            const float ar[4] = {av.x, av.y, av.z, av.w};
            const float br[4] = {bv.x, bv.y, bv.z, bv.w};
            #pragma unroll
            for (int r = 0; r < 4; ++r)
                #pragma unroll
                for (int c = 0; c < 4; ++c)
                    acc[r][c] += ar[r] * br[c];
        }
        __syncthreads();
    }

    float* Yb = Y + (size_t)b * sYb;
    if (YT) {
        #pragma unroll
        for (int c = 0; c < 4; ++c) {
            float4 o4 = make_float4(acc[0][c], acc[1][c], acc[2][c], acc[3][c]);
            *(float4*)&Yb[(size_t)(n0 + tj * 4 + c) * ldy + (m0 + ti * 4)] = o4;
        }
    } else {
        const float* Rb = RES ? (R + (size_t)b * sRb) : nullptr;
        #pragma unroll
        for (int r = 0; r < 4; ++r) {
            float4 o4 = make_float4(acc[r][0], acc[r][1], acc[r][2], acc[r][3]);
            if (SC) {
                o4.x = fminf(fmaxf(o4.x * scalev, -80.f), 80.f);
                o4.y = fminf(fmaxf(o4.y * scalev, -80.f), 80.f);
                o4.z = fminf(fmaxf(o4.z * scalev, -80.f), 80.f);
                o4.w = fminf(fmaxf(o4.w * scalev, -80.f), 80.f);
            }
            size_t off = (size_t)(m0 + ti * 4 + r) * ldy + n0 + tj * 4;
            if (RES) {
                float4 r4 = *(const float4*)&Rb[off];
                o4.x += r4.x; o4.y += r4.y; o4.z += r4.z; o4.w += r4.w;
            }
            *(float4*)&Yb[off] = o4;
        }
    }
}

// ---------------------------------------------------------------------------
// LayerNorm packed rows -> fp32 in-place: P[row][512] u32 -> f32 same buffer
// ---------------------------------------------------------------------------
__global__ __launch_bounds__(256) void ln_rows_packed(u32* __restrict__ P,
                                                      const float* __restrict__ lnw,
                                                      const float* __restrict__ lnb) {
    const int wave = threadIdx.x >> 6, lane = threadIdx.x & 63;
    const int row = blockIdx.x * 4 + wave;
    u32* p = P + (size_t)row * CC;
    uint4 ua = *(uint4*)&p[lane * 4];
    uint4 ub = *(uint4*)&p[256 + lane * 4];
    float4 v0 = make_float4(unpackf(ua.x), unpackf(ua.y), unpackf(ua.z), unpackf(ua.w));
    float4 v1 = make_float4(unpackf(ub.x), unpackf(ub.y), unpackf(ub.z), unpackf(ub.w));
    float s  = v0.x + v0.y + v0.z + v0.w + v1.x + v1.y + v1.z + v1.w;
    float s2 = v0.x*v0.x + v0.y*v0.y + v0.z*v0.z + v0.w*v0.w
             + v1.x*v1.x + v1.y*v1.y + v1.z*v1.z + v1.w*v1.w;
    #pragma unroll
    for (int m = 32; m >= 1; m >>= 1) { s += __shfl_xor(s, m); s2 += __shfl_xor(s2, m); }
    const float mean = s * (1.f / 512.f);
    const float var  = s2 * (1.f / 512.f) - mean * mean;
    const float rstd = rsqrtf(var + LNEPS);
    float4 w0 = *(const float4*)&lnw[lane * 4],        b0 = *(const float4*)&lnb[lane * 4];
    float4 w1 = *(const float4*)&lnw[256 + lane * 4],  b1 = *(const float4*)&lnb[256 + lane * 4];
    v0.x = (v0.x - mean) * rstd * w0.x + b0.x;  v0.y = (v0.y - mean) * rstd * w0.y + b0.y;
    v0.z = (v0.z - mean) * rstd * w0.z + b0.z;  v0.w = (v0.w - mean) * rstd * w0.w + b0.w;
    v1.x = (v1.x - mean) * rstd * w1.x + b1.x;  v1.y = (v1.y - mean) * rstd * w1.y + b1.y;
    v1.z = (v1.z - mean) * rstd * w1.z + b1.z;  v1.w = (v1.w - mean) * rstd * w1.w + b1.w;
    float* q = (float*)p;
    *(float4*)&q[lane * 4] = v0;
    *(float4*)&q[256 + lane * 4] = v1;
}

// ---------------------------------------------------------------------------
// softmax over rows of S[row][256] in-place (one wave per row)
// ---------------------------------------------------------------------------
__global__ __launch_bounds__(256) void softmax_rows(float* __restrict__ S) {
    const int wave = threadIdx.x >> 6, lane = threadIdx.x & 63;
    const int row = blockIdx.x * 4 + wave;
    float* p = S + (size_t)row * KK;
    float4 v = *(float4*)&p[lane * 4];
    float m = fmaxf(fmaxf(v.x, v.y), fmaxf(v.z, v.w));
    #pragma unroll
    for (int mk = 32; mk >= 1; mk >>= 1) m = fmaxf(m, __shfl_xor(m, mk));
    float4 e = make_float4(expf(v.x - m), expf(v.y - m), expf(v.z - m), expf(v.w - m));
    float s = e.x + e.y + e.z + e.w;
    #pragma unroll
    for (int mk = 32; mk >= 1; mk >>= 1) s += __shfl_xor(s, mk);
    const float inv = 1.f / s;
    e.x *= inv; e.y *= inv; e.z *= inv; e.w *= inv;
    *(float4*)&p[lane * 4] = e;
}

// ---------------------------------------------------------------------------
// gather: vsel[b*K+j][c] f32 = unpack(vbufT[b][idx][c])  (contiguous rows)
// ---------------------------------------------------------------------------
__global__ __launch_bounds__(256) void gather_vsel(const u32* __restrict__ VT,
                                                   const int* __restrict__ idx,
                                                   float* __restrict__ Vsel) {
    const int wave = threadIdx.x >> 6, lane = threadIdx.x & 63;
    const int gj = blockIdx.x * 4 + wave;
    const int b = gj >> 8, j = gj & 255;
    const int n = idx[b * KK + j];
    const u32* vp = VT + ((size_t)b * NN + n) * CC;
    float* op = Vsel + (size_t)gj * CC;
    uint4 ua = *(const uint4*)&vp[lane * 8];
    uint4 ub = *(const uint4*)&vp[lane * 8 + 4];
    float4 fa = make_float4(unpackf(ua.x), unpackf(ua.y), unpackf(ua.z), unpackf(ua.w));
    float4 fb = make_float4(unpackf(ub.x), unpackf(ub.y), unpackf(ub.z), unpackf(ub.w));
    *(float4*)&op[lane * 8] = fa;
    *(float4*)&op[lane * 8 + 4] = fb;
}

// ---------------------------------------------------------------------------
// scatter: vbufT[b][idx[i]][c] = pack(att[b*K+i][c])  (contiguous rows)
// ---------------------------------------------------------------------------
__global__ __launch_bounds__(256) void scatter_att(const float* __restrict__ Att,
                                                   const int* __restrict__ idx,
                                                   u32* __restrict__ VT) {
    const int wave = threadIdx.x >> 6, lane = threadIdx.x & 63;
    const int gi = blockIdx.x * 4 + wave;
    const int b = gi >> 8, i = gi & 255;
    const int n = idx[b * KK + i];
    const float* ap = Att + (size_t)gi * CC;
    u32* vp = VT + ((size_t)b * NN + n) * CC;
    float4 fa = *(const float4*)&ap[lane * 8];
    float4 fb = *(const float4*)&ap[lane * 8 + 4];
    uint4 ua, ub;
    ua.x = packf(fa.x); ua.y = packf(fa.y); ua.z = packf(fa.z); ua.w = packf(fa.w);
    ub.x = packf(fb.x); ub.y = packf(fb.y); ub.z = packf(fb.z); ub.w = packf(fb.w);
    *(uint4*)&vp[lane * 8] = ua;
    *(uint4*)&vp[lane * 8 + 4] = ub;
}

// ---------------------------------------------------------------------------
extern "C" void kernel_launch(void* const* d_in, const int* in_sizes, int n_in,
                              void* d_out, int out_size, void* d_ws, size_t ws_size,
                              hipStream_t stream) {
    const float* x   = (const float*)d_in[0];
    const float* wq  = (const float*)d_in[1];
    const float* wk  = (const float*)d_in[2];
    const float* wv  = (const float*)d_in[3];
    const float* wo  = (const float*)d_in[4];
    const float* lnw = (const float*)d_in[5];
    const float* lnb = (const float*)d_in[6];
    float* out = (float*)d_out;

    // workspace layout (bytes); total 113,262,592 (= proven round-7 usage)
    char* w = (char*)d_ws;
    int*   idx   = (int*)w;                             // 16 KB
    float* imp   = (float*)(w + 16384);                 // in 8MB region (also att)
    float* att   = imp;
    u32*   qbufP = (u32*)(w + 8404992);                 // 8 MB (WvH/L first, then qbuf)
    u32*   kbufP = (u32*)(w + 16793600);                // 8 MB (kbuf, then WoH/L)
    float* S     = (float*)(w + 25182208);              // 4 MB
    float* vsel  = (float*)(w + 29376512);              // 8 MB (WqH/L,WkH/L first)
    u32*   vbufT = (u32*)(w + 37765120);                // 75.5 MB packed [b][n][c]
    u16* WvH = (u16*)qbufP;  u16* WvL = WvH + 262144;
    u16* WoH = (u16*)kbufP;  u16* WoL = WoH + 262144;
    u16* WqH = (u16*)vsel;   u16* WqL = WqH + 262144;
    u16* WkH = WqH + 524288; u16* WkL = WqH + 786432;
    u32* XT  = (u32*)d_out;                             // x^T packed, scratch in d_out
    float* qbuf = (float*)qbufP;                        // fp32 after ln_rows_packed
    float* kbuf = (float*)kbufP;

    const long sXp = (long)NN * CC;                     // packed per-batch stride
    const long sQp = (long)KK * CC;
    const long sQ  = (long)KK * CC;
    const long sS  = (long)KK * KK;

    importance_kernel<<<dim3(BB * 9), dim3(256), 0, stream>>>(x, imp);
    topk_kernel<<<dim3(BB), dim3(1024), 0, stream>>>(imp, idx);

    cvt_w<<<dim3(256), dim3(256), 0, stream>>>(wv, WvH, WvL);
    cvt_w<<<dim3(256), dim3(256), 0, stream>>>(wq, WqH, WqL);
    cvt_w<<<dim3(256), dim3(256), 0, stream>>>(wk, WkH, WkL);
    transpose_cvt<<<dim3(NN / 64, CC / 64, BB), dim3(256), 0, stream>>>(x, XT);

    // V-projection: vbufT[n][c] = pack( (wv @ x)^T )   [swizzled, 18*4*16 blocks]
    mfma_gemm<0><<<dim3(18 * 4 * BB), dim3(256), 0, stream>>>(
        WvH, WvL, XT, sXp, 18, nullptr, nullptr, (void*)vbufT, sXp);

    // q/k projections on selected columns (indexed B gather), packed [k][c]
    mfma_gemm<0><<<dim3(2 * 4 * BB), dim3(256), 0, stream>>>(
        WqH, WqL, XT, sXp, 2, idx, nullptr, (void*)qbufP, sQp);
    mfma_gemm<0><<<dim3(2 * 4 * BB), dim3(256), 0, stream>>>(
        WkH, WkL, XT, sXp, 2, idx, nullptr, (void*)kbufP, sQp);

    // layernorm packed -> fp32 in-place
    ln_rows_packed<<<dim3(BB * KK / 4), dim3(256), 0, stream>>>(qbufP, lnw, lnb);
    ln_rows_packed<<<dim3(BB * KK / 4), dim3(256), 0, stream>>>(kbufP, lnw, lnb);

    // attention logits S = clip(scale * Qn Kn^T)
    tile_gemm<true,false,true,false><<<dim3(KK/64, KK/64, BB), dim3(256), 0, stream>>>(
        qbuf, sQ, CC, kbuf, sQ, CC, nullptr, 0, S, sS, KK, CC, SCALE);
    softmax_rows<<<dim3(BB * KK / 4), dim3(256), 0, stream>>>(S);

    gather_vsel<<<dim3(BB * KK / 4), dim3(256), 0, stream>>>(vbufT, idx, vsel);
    // attended = P @ vsel -> att[b][i][c]
    tile_gemm<false,false,false,false><<<dim3(CC/64, KK/64, BB), dim3(256), 0, stream>>>(
        S, sS, KK, vsel, sQ, CC, nullptr, 0, att, sQ, CC, KK, 1.f);
    scatter_att<<<dim3(BB * KK / 4), dim3(256), 0, stream>>>(att, idx, vbufT);

    cvt_w<<<dim3(256), dim3(256), 0, stream>>>(wo, WoH, WoL);
    // O-projection: out[c][n] = x + wo @ vbuf   [swizzled]
    mfma_gemm<1><<<dim3(18 * 4 * BB), dim3(256), 0, stream>>>(
        WoH, WoL, vbufT, sXp, 18, nullptr, x, (void*)out, (long)CC * NN);
}

// Round 11
// 527.122 us; speedup vs baseline: 1.7036x; 1.0079x over previous
//
#include <hip/hip_runtime.h>
#include <hip/hip_bf16.h>

// Problem constants (B,C,H,W)=(16,512,48,48), K_TOP=256, eps=1e-5
#define BB   16
#define CC   512
#define NN   2304
#define KK   256
#define LNEPS 1e-5f
#define SCALE 0.04419417382415922f   // 512^-0.5

typedef unsigned int  u32;
typedef unsigned short u16;
typedef __attribute__((ext_vector_type(8))) short short8;
typedef __attribute__((ext_vector_type(4))) float f32x4;

// ---------------- bf16 split helpers (RNE) ----------------
__device__ __forceinline__ u32 f2bf_u(float f) {
    u32 u = __float_as_uint(f);
    return (u + 0x7fffu + ((u >> 16) & 1u)) >> 16;
}
__device__ __forceinline__ u32 packf(float f) {
    u32 h = f2bf_u(f);
    float hf = __uint_as_float(h << 16);
    u32 l = f2bf_u(f - hf);
    return h | (l << 16);
}
__device__ __forceinline__ float unpackf(u32 p) {
    return __uint_as_float(p << 16) + __uint_as_float(p & 0xffff0000u);
}

__device__ __forceinline__ void gl16(const void* g, void* l) {
    __builtin_amdgcn_global_load_lds((const __attribute__((address_space(1))) u32*)g,
                                     (__attribute__((address_space(3))) u32*)l, 16, 0, 0);
}

// ---------------------------------------------------------------------------
// 1) importance[b,n] = sum_c x[b,c,n]^2  (fp64 accumulate for stable ordering)
// ---------------------------------------------------------------------------
__global__ __launch_bounds__(256) void importance_kernel(const float* __restrict__ X,
                                                         float* __restrict__ imp) {
    int b = blockIdx.x / 9;
    int n = (blockIdx.x % 9) * 256 + threadIdx.x;
    const float* xp = X + (size_t)b * CC * NN + n;
    double s = 0.0;
    #pragma unroll 8
    for (int c = 0; c < CC; ++c) {
        float v = xp[(size_t)c * NN];
        s = fma((double)v, (double)v, s);
    }
    imp[b * NN + n] = (float)s;
}

// ---------------------------------------------------------------------------
// 2) per-batch top-256 via bitonic sort (ties -> smaller idx, matches top_k)
// ---------------------------------------------------------------------------
__global__ __launch_bounds__(1024) void topk_kernel(const float* __restrict__ imp,
                                                    int* __restrict__ idx) {
    __shared__ unsigned long long keys[4096];
    const int b = blockIdx.x, tid = threadIdx.x;
    for (int i = tid; i < 4096; i += 1024) {
        unsigned long long kv = 0ULL;
        if (i < NN) {
            unsigned u = __float_as_uint(imp[b * NN + i]);
            u = (u & 0x80000000u) ? ~u : (u | 0x80000000u);
            kv = ((unsigned long long)u << 32) | (unsigned)(NN - 1 - i);
        }
        keys[i] = kv;
    }
    __syncthreads();
    for (int k = 2; k <= 4096; k <<= 1) {
        for (int j = k >> 1; j > 0; j >>= 1) {
            for (int i = tid; i < 4096; i += 1024) {
                int l = i ^ j;
                if (l > i) {
                    unsigned long long a = keys[i], c = keys[l];
                    bool desc = ((i & k) == 0);
                    if (desc ? (a < c) : (a > c)) { keys[i] = c; keys[l] = a; }
                }
            }
            __syncthreads();
        }
    }
    if (tid < KK) idx[b * KK + tid] = NN - 1 - (int)(keys[tid] & 0xffffffffu);
}

// ---------------------------------------------------------------------------
// 3) transpose-convert: x[b][c][n] f32 -> XT[b][n][c] u32 (bf16 hi | lo<<16)
// ---------------------------------------------------------------------------
__global__ __launch_bounds__(256) void transpose_cvt(const float* __restrict__ X,
                                                     u32* __restrict__ XT) {
    __shared__ u32 T[64 * 65];
    const int b = blockIdx.z;
    const int n0 = blockIdx.x * 64, c0 = blockIdx.y * 64;
    const int t = threadIdx.x;
    const int cl = t >> 4, nl4 = (t & 15) * 4;
    #pragma unroll
    for (int p = 0; p < 4; ++p) {
        int c = cl + 16 * p;
        float4 v = *(const float4*)&X[((size_t)(b * CC + c0 + c)) * NN + n0 + nl4];
        T[c * 65 + nl4 + 0] = packf(v.x);
        T[c * 65 + nl4 + 1] = packf(v.y);
        T[c * 65 + nl4 + 2] = packf(v.z);
        T[c * 65 + nl4 + 3] = packf(v.w);
    }
    __syncthreads();
    const int cch = t & 15;
    #pragma unroll
    for (int q = 0; q < 4; ++q) {
        int n = (t >> 4) + 16 * q;
        uint4 o;
        o.x = T[(cch * 4 + 0) * 65 + n];
        o.y = T[(cch * 4 + 1) * 65 + n];
        o.z = T[(cch * 4 + 2) * 65 + n];
        o.w = T[(cch * 4 + 3) * 65 + n];
        *(uint4*)&XT[((size_t)b * NN + n0 + n) * CC + c0 + cch * 4] = o;
    }
}

// ---------------------------------------------------------------------------
// 4) weight convert: W[512][512] f32 -> Wh, Wl bf16-bit arrays (k-contiguous)
// ---------------------------------------------------------------------------
__global__ __launch_bounds__(256) void cvt_w(const float* __restrict__ W,
                                             u16* __restrict__ Wh, u16* __restrict__ Wl) {
    int i4 = (blockIdx.x * 256 + threadIdx.x) * 4;
    float4 v = *(const float4*)&W[i4];
    ushort4 h, l;
    h.x = (u16)f2bf_u(v.x); l.x = (u16)f2bf_u(v.x - __uint_as_float((u32)h.x << 16));
    h.y = (u16)f2bf_u(v.y); l.y = (u16)f2bf_u(v.y - __uint_as_float((u32)h.y << 16));
    h.z = (u16)f2bf_u(v.z); l.z = (u16)f2bf_u(v.z - __uint_as_float((u32)h.z << 16));
    h.w = (u16)f2bf_u(v.w); l.w = (u16)f2bf_u(v.w - __uint_as_float((u32)h.w << 16));
    *(ushort4*)&Wh[i4] = h;
    *(ushort4*)&Wl[i4] = l;
}

// ---------------------------------------------------------------------------
// 5) Split-bf16 MFMA GEMM, 2-phase double-buffered pipeline (T3-min):
//    issue next K-tile's global_load_lds BEFORE computing current tile;
//    ONE barrier per K-step (its auto vmcnt(0)/lgkmcnt(0) drain is the wait).
//    XCD-bijective grid swizzle for B-slab L2 reuse (R8: FETCH 197->85 MB).
//    rowidx != nullptr: B row n gathered as rowidx[b*KK+n] (q/k path).
//    EPI=0: Y packed u32 [n][c].  EPI=1: Y f32 [c][n] + residual.
// ---------------------------------------------------------------------------
template<int EPI>
__global__ __launch_bounds__(256) void mfma_gemm(
    const u16* __restrict__ Ah, const u16* __restrict__ Al,
    const u32* __restrict__ Bpk, long sBb, int nbN,
    const int* __restrict__ rowidx,
    const float* __restrict__ Xres,
    void* __restrict__ Yv, long sYb)
{
    __shared__ u16 sAh[2][128 * 32];
    __shared__ u16 sAl[2][128 * 32];
    __shared__ u32 sB[2][128 * 32];
    // swizzle: lin = xcd + 8*slot + 32*grp ; pair p = grp*8 + xcd ; c_blk = slot
    const int lin = blockIdx.x;
    const int xcd = lin & 7, slot = (lin >> 3) & 3, grp = lin >> 5;
    const int p = grp * 8 + xcd;
    const int b = p / nbN, nb = p - b * nbN;
    const int n0 = nb * 128;
    const int c0 = slot * 128;
    const int t = threadIdx.x;
    const int wid = t >> 6, lane = t & 63;
    const int mw = (wid >> 1) * 64, nw = (wid & 1) * 64;
    const int lm = lane & 15, lk = lane >> 4;
    const u32* Bb = Bpk + (size_t)b * sBb;

    // hoist the 4 B-row base offsets (gathered for q/k path)
    size_t brow[4];
    #pragma unroll
    for (int i = 0; i < 4; ++i) {
        int r = (t >> 3) + 32 * i;
        int gr = rowidx ? rowidx[b * KK + n0 + r] : (n0 + r);
        brow[i] = (size_t)gr * CC;
    }

    f32x4 acc[4][4] = {};

    auto STAGE = [&](int buf, int k0) {
        #pragma unroll
        for (int i = 0; i < 2; ++i) {          // A tiles: 2x 8KB each array
            int e = t + 256 * i, r = e >> 2, ch = e & 3;
            int gch = ch ^ (r & 3);            // pre-swizzled source chunk
            gl16(&Ah[(size_t)(c0 + r) * 512 + k0 + gch * 8], &sAh[buf][e * 8]);
            gl16(&Al[(size_t)(c0 + r) * 512 + k0 + gch * 8], &sAl[buf][e * 8]);
        }
        #pragma unroll
        for (int i = 0; i < 4; ++i) {          // B tile: 16KB
            int e = t + 256 * i, ch = e & 7;
            int r = (t >> 3) + 32 * i;         // LDS row
            int gch = ch ^ (r & 7);
            gl16(&Bb[brow[i] + k0 + gch * 4], &sB[buf][e * 4]);
        }
    };

    auto COMPUTE = [&](int buf) {
        short8 ah[4], al[4], bh[4], bl[4];
        #pragma unroll
        for (int i = 0; i < 4; ++i) {
            int m = mw + 16 * i + lm;
            int ach = lk ^ (m & 3);            // swizzled read
            ah[i] = *(const short8*)&sAh[buf][m * 32 + ach * 8];
            al[i] = *(const short8*)&sAl[buf][m * 32 + ach * 8];
        }
        #pragma unroll
        for (int j = 0; j < 4; ++j) {
            int n = nw + 16 * j + lm;
            const u32* prow = &sB[buf][n * 32];
            int ca = (2 * lk) ^ (n & 7);
            int cb = (2 * lk + 1) ^ (n & 7);
            uint4 u0 = *(const uint4*)&prow[ca * 4];   // k 0..3 (hi|lo packed)
            uint4 u1 = *(const uint4*)&prow[cb * 4];   // k 4..7
            union { u32 u[4]; short8 s; } H, L;
            H.u[0] = __builtin_amdgcn_perm(u0.y, u0.x, 0x05040100u);
            H.u[1] = __builtin_amdgcn_perm(u0.w, u0.z, 0x05040100u);
            H.u[2] = __builtin_amdgcn_perm(u1.y, u1.x, 0x05040100u);
            H.u[3] = __builtin_amdgcn_perm(u1.w, u1.z, 0x05040100u);
            L.u[0] = __builtin_amdgcn_perm(u0.y, u0.x, 0x07060302u);
            L.u[1] = __builtin_amdgcn_perm(u0.w, u0.z, 0x07060302u);
            L.u[2] = __builtin_amdgcn_perm(u1.y, u1.x, 0x07060302u);
            L.u[3] = __builtin_amdgcn_perm(u1.w, u1.z, 0x07060302u);
            bh[j] = H.s; bl[j] = L.s;
        }
        #pragma unroll
        for (int i = 0; i < 4; ++i)
            #pragma unroll
            for (int j = 0; j < 4; ++j) {
                acc[i][j] = __builtin_amdgcn_mfma_f32_16x16x32_bf16(ah[i], bh[j], acc[i][j], 0, 0, 0);
                acc[i][j] = __builtin_amdgcn_mfma_f32_16x16x32_bf16(ah[i], bl[j], acc[i][j], 0, 0, 0);
                acc[i][j] = __builtin_amdgcn_mfma_f32_16x16x32_bf16(al[i], bh[j], acc[i][j], 0, 0, 0);
            }
    };

    // prologue: stage first tile into buf0
    STAGE(0, 0);
    __syncthreads();                            // auto vmcnt(0) drain
    // 16 K-steps, explicit 2x body so buffer indices are compile-time
    for (int ks = 0; ks < 16; ks += 2) {
        STAGE(1, (ks + 1) * 32);                // prefetch next (ks+1 <= 15 always)
        COMPUTE(0);
        __syncthreads();                        // drains prefetch + syncs LDS reads
        if (ks < 14) STAGE(0, (ks + 2) * 32);
        COMPUTE(1);
        __syncthreads();
    }

    if (EPI == 0) {
        u32* Y = (u32*)Yv + (size_t)b * sYb;
        #pragma unroll
        for (int i = 0; i < 4; ++i)
            #pragma unroll
            for (int j = 0; j < 4; ++j) {
                uint4 o;
                o.x = packf(acc[i][j][0]);
                o.y = packf(acc[i][j][1]);
                o.z = packf(acc[i][j][2]);
                o.w = packf(acc[i][j][3]);
                *(uint4*)&Y[(size_t)(n0 + nw + 16 * j + lm) * CC + c0 + mw + 16 * i + 4 * lk] = o;
            }
    } else {
        float* Y = (float*)Yv + (size_t)b * sYb;
        const float* Xb = Xres + (size_t)b * sYb;
        #pragma unroll
        for (int i = 0; i < 4; ++i)
            #pragma unroll
            for (int r = 0; r < 4; ++r) {
                size_t roff = (size_t)(c0 + mw + 16 * i + 4 * lk + r) * NN;
                #pragma unroll
                for (int j = 0; j < 4; ++j) {
                    size_t off = roff + n0 + nw + 16 * j + lm;
                    Y[off] = acc[i][j][r] + Xb[off];
                }
            }
    }
}

// ---------------------------------------------------------------------------
// fp32 tiled GEMM (for S and PV)
// ---------------------------------------------------------------------------
template<bool BT, bool RES, bool SC, bool YT>
__global__ __launch_bounds__(256) void tile_gemm(
    const float* __restrict__ A, long sAb, int lda,
    const float* __restrict__ Bm, long sBb, int ldb,
    const float* __restrict__ R, long sRb,
    float* __restrict__ Y, long sYb, int ldy,
    int Kd, float scalev)
{
    __shared__ float At[16][68];
    __shared__ float Bt[16][68];
    const int b  = blockIdx.z;
    const int n0 = blockIdx.x * 64;
    const int m0 = blockIdx.y * 64;
    const int tid = threadIdx.x;
    const int ti = tid >> 4, tj = tid & 15;
    const int arow = tid >> 2, akk = (tid & 3) << 2;
    const int bkk  = tid >> 4, bjx = (tid & 15) << 2;
    const float* Ab = A  + (size_t)b * sAb;
    const float* Bb = Bm + (size_t)b * sBb;
    float acc[4][4] = {{0.f}};

    for (int k0 = 0; k0 < Kd; k0 += 16) {
        float4 a4 = *(const float4*)&Ab[(size_t)(m0 + arow) * lda + k0 + akk];
        At[akk + 0][arow] = a4.x; At[akk + 1][arow] = a4.y;
        At[akk + 2][arow] = a4.z; At[akk + 3][arow] = a4.w;
        if (BT) {
            float4 b4 = *(const float4*)&Bb[(size_t)(n0 + arow) * ldb + k0 + akk];
            Bt[akk + 0][arow] = b4.x; Bt[akk + 1][arow] = b4.y;
            Bt[akk + 2][arow] = b4.z; Bt[akk + 3][arow] = b4.w;
        } else {
            *(float4*)&Bt[bkk][bjx] = *(const float4*)&Bb[(size_t)(k0 + bkk) * ldb + n0 + bjx];
        }
        __syncthreads();
        #pragma unroll
        for (int kk = 0; kk < 16; ++kk) {
            const float4 av = *(const float4*)&At[kk][ti * 4];
            const float4 bv = *(const float4*)&Bt[kk][tj * 4];
            const float ar[4] = {av.x, av.y, av.z, av.w};
            const float br[4] = {bv.x, bv.y, bv.z, bv.w};
            #pragma unroll
            for (int r = 0; r < 4; ++r)
                #pragma unroll
                for (int c = 0; c < 4; ++c)
                    acc[r][c] += ar[r] * br[c];
        }
        __syncthreads();
    }

    float* Yb = Y + (size_t)b * sYb;
    if (YT) {
        #pragma unroll
        for (int c = 0; c < 4; ++c) {
            float4 o4 = make_float4(acc[0][c], acc[1][c], acc[2][c], acc[3][c]);
            *(float4*)&Yb[(size_t)(n0 + tj * 4 + c) * ldy + (m0 + ti * 4)] = o4;
        }
    } else {
        const float* Rb = RES ? (R + (size_t)b * sRb) : nullptr;
        #pragma unroll
        for (int r = 0; r < 4; ++r) {
            float4 o4 = make_float4(acc[r][0], acc[r][1], acc[r][2], acc[r][3]);
            if (SC) {
                o4.x = fminf(fmaxf(o4.x * scalev, -80.f), 80.f);
                o4.y = fminf(fmaxf(o4.y * scalev, -80.f), 80.f);
                o4.z = fminf(fmaxf(o4.z * scalev, -80.f), 80.f);
                o4.w = fminf(fmaxf(o4.w * scalev, -80.f), 80.f);
            }
            size_t off = (size_t)(m0 + ti * 4 + r) * ldy + n0 + tj * 4;
            if (RES) {
                float4 r4 = *(const float4*)&Rb[off];
                o4.x += r4.x; o4.y += r4.y; o4.z += r4.z; o4.w += r4.w;
            }
            *(float4*)&Yb[off] = o4;
        }
    }
}

// ---------------------------------------------------------------------------
// LayerNorm packed rows -> fp32 in-place: P[row][512] u32 -> f32 same buffer
// ---------------------------------------------------------------------------
__global__ __launch_bounds__(256) void ln_rows_packed(u32* __restrict__ P,
                                                      const float* __restrict__ lnw,
                                                      const float* __restrict__ lnb) {
    const int wave = threadIdx.x >> 6, lane = threadIdx.x & 63;
    const int row = blockIdx.x * 4 + wave;
    u32* p = P + (size_t)row * CC;
    uint4 ua = *(uint4*)&p[lane * 4];
    uint4 ub = *(uint4*)&p[256 + lane * 4];
    float4 v0 = make_float4(unpackf(ua.x), unpackf(ua.y), unpackf(ua.z), unpackf(ua.w));
    float4 v1 = make_float4(unpackf(ub.x), unpackf(ub.y), unpackf(ub.z), unpackf(ub.w));
    float s  = v0.x + v0.y + v0.z + v0.w + v1.x + v1.y + v1.z + v1.w;
    float s2 = v0.x*v0.x + v0.y*v0.y + v0.z*v0.z + v0.w*v0.w
             + v1.x*v1.x + v1.y*v1.y + v1.z*v1.z + v1.w*v1.w;
    #pragma unroll
    for (int m = 32; m >= 1; m >>= 1) { s += __shfl_xor(s, m); s2 += __shfl_xor(s2, m); }
    const float mean = s * (1.f / 512.f);
    const float var  = s2 * (1.f / 512.f) - mean * mean;
    const float rstd = rsqrtf(var + LNEPS);
    float4 w0 = *(const float4*)&lnw[lane * 4],        b0 = *(const float4*)&lnb[lane * 4];
    float4 w1 = *(const float4*)&lnw[256 + lane * 4],  b1 = *(const float4*)&lnb[256 + lane * 4];
    v0.x = (v0.x - mean) * rstd * w0.x + b0.x;  v0.y = (v0.y - mean) * rstd * w0.y + b0.y;
    v0.z = (v0.z - mean) * rstd * w0.z + b0.z;  v0.w = (v0.w - mean) * rstd * w0.w + b0.w;
    v1.x = (v1.x - mean) * rstd * w1.x + b1.x;  v1.y = (v1.y - mean) * rstd * w1.y + b1.y;
    v1.z = (v1.z - mean) * rstd * w1.z + b1.z;  v1.w = (v1.w - mean) * rstd * w1.w + b1.w;
    float* q = (float*)p;
    *(float4*)&q[lane * 4] = v0;
    *(float4*)&q[256 + lane * 4] = v1;
}

// ---------------------------------------------------------------------------
// softmax over rows of S[row][256] in-place (one wave per row)
// ---------------------------------------------------------------------------
__global__ __launch_bounds__(256) void softmax_rows(float* __restrict__ S) {
    const int wave = threadIdx.x >> 6, lane = threadIdx.x & 63;
    const int row = blockIdx.x * 4 + wave;
    float* p = S + (size_t)row * KK;
    float4 v = *(float4*)&p[lane * 4];
    float m = fmaxf(fmaxf(v.x, v.y), fmaxf(v.z, v.w));
    #pragma unroll
    for (int mk = 32; mk >= 1; mk >>= 1) m = fmaxf(m, __shfl_xor(m, mk));
    float4 e = make_float4(expf(v.x - m), expf(v.y - m), expf(v.z - m), expf(v.w - m));
    float s = e.x + e.y + e.z + e.w;
    #pragma unroll
    for (int mk = 32; mk >= 1; mk >>= 1) s += __shfl_xor(s, mk);
    const float inv = 1.f / s;
    e.x *= inv; e.y *= inv; e.z *= inv; e.w *= inv;
    *(float4*)&p[lane * 4] = e;
}

// ---------------------------------------------------------------------------
// gather: vsel[b*K+j][c] f32 = unpack(vbufT[b][idx][c])  (contiguous rows)
// ---------------------------------------------------------------------------
__global__ __launch_bounds__(256) void gather_vsel(const u32* __restrict__ VT,
                                                   const int* __restrict__ idx,
                                                   float* __restrict__ Vsel) {
    const int wave = threadIdx.x >> 6, lane = threadIdx.x & 63;
    const int gj = blockIdx.x * 4 + wave;
    const int b = gj >> 8, j = gj & 255;
    const int n = idx[b * KK + j];
    const u32* vp = VT + ((size_t)b * NN + n) * CC;
    float* op = Vsel + (size_t)gj * CC;
    uint4 ua = *(const uint4*)&vp[lane * 8];
    uint4 ub = *(const uint4*)&vp[lane * 8 + 4];
    float4 fa = make_float4(unpackf(ua.x), unpackf(ua.y), unpackf(ua.z), unpackf(ua.w));
    float4 fb = make_float4(unpackf(ub.x), unpackf(ub.y), unpackf(ub.z), unpackf(ub.w));
    *(float4*)&op[lane * 8] = fa;
    *(float4*)&op[lane * 8 + 4] = fb;
}

// ---------------------------------------------------------------------------
// scatter: vbufT[b][idx[i]][c] = pack(att[b*K+i][c])  (contiguous rows)
// ---------------------------------------------------------------------------
__global__ __launch_bounds__(256) void scatter_att(const float* __restrict__ Att,
                                                   const int* __restrict__ idx,
                                                   u32* __restrict__ VT) {
    const int wave = threadIdx.x >> 6, lane = threadIdx.x & 63;
    const int gi = blockIdx.x * 4 + wave;
    const int b = gi >> 8, i = gi & 255;
    const int n = idx[b * KK + i];
    const float* ap = Att + (size_t)gi * CC;
    u32* vp = VT + ((size_t)b * NN + n) * CC;
    float4 fa = *(const float4*)&ap[lane * 8];
    float4 fb = *(const float4*)&ap[lane * 8 + 4];
    uint4 ua, ub;
    ua.x = packf(fa.x); ua.y = packf(fa.y); ua.z = packf(fa.z); ua.w = packf(fa.w);
    ub.x = packf(fb.x); ub.y = packf(fb.y); ub.z = packf(fb.z); ub.w = packf(fb.w);
    *(uint4*)&vp[lane * 8] = ua;
    *(uint4*)&vp[lane * 8 + 4] = ub;
}

// ---------------------------------------------------------------------------
extern "C" void kernel_launch(void* const* d_in, const int* in_sizes, int n_in,
                              void* d_out, int out_size, void* d_ws, size_t ws_size,
                              hipStream_t stream) {
    const float* x   = (const float*)d_in[0];
    const float* wq  = (const float*)d_in[1];
    const float* wk  = (const float*)d_in[2];
    const float* wv  = (const float*)d_in[3];
    const float* wo  = (const float*)d_in[4];
    const float* lnw = (const float*)d_in[5];
    const float* lnb = (const float*)d_in[6];
    float* out = (float*)d_out;

    // workspace layout (bytes); total 113,262,592 (= proven round-7 usage)
    char* w = (char*)d_ws;
    int*   idx   = (int*)w;                             // 16 KB
    float* imp   = (float*)(w + 16384);                 // in 8MB region (also att)
    float* att   = imp;
    u32*   qbufP = (u32*)(w + 8404992);                 // 8 MB (WvH/L first, then qbuf)
    u32*   kbufP = (u32*)(w + 16793600);                // 8 MB (kbuf, then WoH/L)
    float* S     = (float*)(w + 25182208);              // 4 MB
    float* vsel  = (float*)(w + 29376512);              // 8 MB (WqH/L,WkH/L first)
    u32*   vbufT = (u32*)(w + 37765120);                // 75.5 MB packed [b][n][c]
    u16* WvH = (u16*)qbufP;  u16* WvL = WvH + 262144;
    u16* WoH = (u16*)kbufP;  u16* WoL = WoH + 262144;
    u16* WqH = (u16*)vsel;   u16* WqL = WqH + 262144;
    u16* WkH = WqH + 524288; u16* WkL = WqH + 786432;
    u32* XT  = (u32*)d_out;                             // x^T packed, scratch in d_out
    float* qbuf = (float*)qbufP;                        // fp32 after ln_rows_packed
    float* kbuf = (float*)kbufP;

    const long sXp = (long)NN * CC;                     // packed per-batch stride
    const long sQp = (long)KK * CC;
    const long sQ  = (long)KK * CC;
    const long sS  = (long)KK * KK;

    importance_kernel<<<dim3(BB * 9), dim3(256), 0, stream>>>(x, imp);
    topk_kernel<<<dim3(BB), dim3(1024), 0, stream>>>(imp, idx);

    cvt_w<<<dim3(256), dim3(256), 0, stream>>>(wv, WvH, WvL);
    cvt_w<<<dim3(256), dim3(256), 0, stream>>>(wq, WqH, WqL);
    cvt_w<<<dim3(256), dim3(256), 0, stream>>>(wk, WkH, WkL);
    transpose_cvt<<<dim3(NN / 64, CC / 64, BB), dim3(256), 0, stream>>>(x, XT);

    // V-projection: vbufT[n][c] = pack( (wv @ x)^T )   [swizzled, 18*4*16 blocks]
    mfma_gemm<0><<<dim3(18 * 4 * BB), dim3(256), 0, stream>>>(
        WvH, WvL, XT, sXp, 18, nullptr, nullptr, (void*)vbufT, sXp);

    // q/k projections on selected columns (indexed B gather), packed [k][c]
    mfma_gemm<0><<<dim3(2 * 4 * BB), dim3(256), 0, stream>>>(
        WqH, WqL, XT, sXp, 2, idx, nullptr, (void*)qbufP, sQp);
    mfma_gemm<0><<<dim3(2 * 4 * BB), dim3(256), 0, stream>>>(
        WkH, WkL, XT, sXp, 2, idx, nullptr, (void*)kbufP, sQp);

    // layernorm packed -> fp32 in-place
    ln_rows_packed<<<dim3(BB * KK / 4), dim3(256), 0, stream>>>(qbufP, lnw, lnb);
    ln_rows_packed<<<dim3(BB * KK / 4), dim3(256), 0, stream>>>(kbufP, lnw, lnb);

    // attention logits S = clip(scale * Qn Kn^T)
    tile_gemm<true,false,true,false><<<dim3(KK/64, KK/64, BB), dim3(256), 0, stream>>>(
        qbuf, sQ, CC, kbuf, sQ, CC, nullptr, 0, S, sS, KK, CC, SCALE);
    softmax_rows<<<dim3(BB * KK / 4), dim3(256), 0, stream>>>(S);

    gather_vsel<<<dim3(BB * KK / 4), dim3(256), 0, stream>>>(vbufT, idx, vsel);
    // attended = P @ vsel -> att[b][i][c]
    tile_gemm<false,false,false,false><<<dim3(CC/64, KK/64, BB), dim3(256), 0, stream>>>(
        S, sS, KK, vsel, sQ, CC, nullptr, 0, att, sQ, CC, KK, 1.f);
    scatter_att<<<dim3(BB * KK / 4), dim3(256), 0, stream>>>(att, idx, vbufT);

    cvt_w<<<dim3(256), dim3(256), 0, stream>>>(wo, WoH, WoL);
    // O-projection: out[c][n] = x + wo @ vbuf   [swizzled]
    mfma_gemm<1><<<dim3(18 * 4 * BB), dim3(256), 0, stream>>>(
        WoH, WoL, vbufT, sXp, 18, nullptr, x, (void*)out, (long)CC * NN);
}

// Round 12
// 507.003 us; speedup vs baseline: 1.7712x; 1.0397x over previous
//
#include <hip/hip_runtime.h>
#include <hip/hip_bf16.h>

// Problem constants (B,C,H,W)=(16,512,48,48), K_TOP=256, eps=1e-5
#define BB   16
#define CC   512
#define NN   2304
#define KK   256
#define LNEPS 1e-5f
#define SCALE 0.04419417382415922f   // 512^-0.5

typedef unsigned int  u32;
typedef unsigned short u16;
typedef __attribute__((ext_vector_type(8))) short short8;
typedef __attribute__((ext_vector_type(4))) float f32x4;

// ---------------- bf16 split helpers (RNE) ----------------
__device__ __forceinline__ u32 f2bf_u(float f) {
    u32 u = __float_as_uint(f);
    return (u + 0x7fffu + ((u >> 16) & 1u)) >> 16;
}
__device__ __forceinline__ u32 packf(float f) {
    u32 h = f2bf_u(f);
    float hf = __uint_as_float(h << 16);
    u32 l = f2bf_u(f - hf);
    return h | (l << 16);
}
__device__ __forceinline__ float unpackf(u32 p) {
    return __uint_as_float(p << 16) + __uint_as_float(p & 0xffff0000u);
}

__device__ __forceinline__ void gl16(const void* g, void* l) {
    __builtin_amdgcn_global_load_lds((const __attribute__((address_space(1))) u32*)g,
                                     (__attribute__((address_space(3))) u32*)l, 16, 0, 0);
}

// ---------------------------------------------------------------------------
// 1) fused transpose-convert + importance:
//    XT[b][n][c] u32 (bf16 hi|lo)  and  impd[b][n] += sum_c x^2 (f64 atomics)
// ---------------------------------------------------------------------------
__global__ __launch_bounds__(256) void transpose_imp(const float* __restrict__ X,
                                                     u32* __restrict__ XT,
                                                     double* __restrict__ impd) {
    __shared__ u32 T[64 * 65];
    __shared__ double S2[16][65];
    const int b = blockIdx.z;
    const int n0 = blockIdx.x * 64, c0 = blockIdx.y * 64;
    const int t = threadIdx.x;
    const int cl = t >> 4, nl4 = (t & 15) * 4;
    double p0 = 0.0, p1 = 0.0, p2 = 0.0, p3 = 0.0;
    #pragma unroll
    for (int p = 0; p < 4; ++p) {
        int c = cl + 16 * p;
        float4 v = *(const float4*)&X[((size_t)(b * CC + c0 + c)) * NN + n0 + nl4];
        T[c * 65 + nl4 + 0] = packf(v.x);
        T[c * 65 + nl4 + 1] = packf(v.y);
        T[c * 65 + nl4 + 2] = packf(v.z);
        T[c * 65 + nl4 + 3] = packf(v.w);
        p0 += (double)v.x * v.x;
        p1 += (double)v.y * v.y;
        p2 += (double)v.z * v.z;
        p3 += (double)v.w * v.w;
    }
    S2[cl][nl4 + 0] = p0;
    S2[cl][nl4 + 1] = p1;
    S2[cl][nl4 + 2] = p2;
    S2[cl][nl4 + 3] = p3;
    __syncthreads();
    const int cch = t & 15;
    #pragma unroll
    for (int q = 0; q < 4; ++q) {
        int n = (t >> 4) + 16 * q;
        uint4 o;
        o.x = T[(cch * 4 + 0) * 65 + n];
        o.y = T[(cch * 4 + 1) * 65 + n];
        o.z = T[(cch * 4 + 2) * 65 + n];
        o.w = T[(cch * 4 + 3) * 65 + n];
        *(uint4*)&XT[((size_t)b * NN + n0 + n) * CC + c0 + cch * 4] = o;
    }
    if (t < 64) {
        double s = 0.0;
        #pragma unroll
        for (int c2 = 0; c2 < 16; ++c2) s += S2[c2][t];
        atomicAdd(&impd[b * NN + n0 + t], s);
    }
}

// ---------------------------------------------------------------------------
// 2) per-batch top-256 via bitonic sort (ties -> smaller idx, matches top_k)
// ---------------------------------------------------------------------------
__global__ __launch_bounds__(1024) void topk_kernel(const double* __restrict__ impd,
                                                    int* __restrict__ idx) {
    __shared__ unsigned long long keys[4096];
    const int b = blockIdx.x, tid = threadIdx.x;
    for (int i = tid; i < 4096; i += 1024) {
        unsigned long long kv = 0ULL;
        if (i < NN) {
            float fv = (float)impd[b * NN + i];
            unsigned u = __float_as_uint(fv);
            u = (u & 0x80000000u) ? ~u : (u | 0x80000000u);
            kv = ((unsigned long long)u << 32) | (unsigned)(NN - 1 - i);
        }
        keys[i] = kv;
    }
    __syncthreads();
    for (int k = 2; k <= 4096; k <<= 1) {
        for (int j = k >> 1; j > 0; j >>= 1) {
            for (int i = tid; i < 4096; i += 1024) {
                int l = i ^ j;
                if (l > i) {
                    unsigned long long a = keys[i], c = keys[l];
                    bool desc = ((i & k) == 0);
                    if (desc ? (a < c) : (a > c)) { keys[i] = c; keys[l] = a; }
                }
            }
            __syncthreads();
        }
    }
    if (tid < KK) idx[b * KK + tid] = NN - 1 - (int)(keys[tid] & 0xffffffffu);
}

// ---------------------------------------------------------------------------
// 3) weight convert x3 (wv,wq,wk): f32 -> Wh, Wl bf16-bit arrays
// ---------------------------------------------------------------------------
__device__ __forceinline__ void cvt_one(const float* W, u16* Wh, u16* Wl, int i4) {
    float4 v = *(const float4*)&W[i4];
    ushort4 h, l;
    h.x = (u16)f2bf_u(v.x); l.x = (u16)f2bf_u(v.x - __uint_as_float((u32)h.x << 16));
    h.y = (u16)f2bf_u(v.y); l.y = (u16)f2bf_u(v.y - __uint_as_float((u32)h.y << 16));
    h.z = (u16)f2bf_u(v.z); l.z = (u16)f2bf_u(v.z - __uint_as_float((u32)h.z << 16));
    h.w = (u16)f2bf_u(v.w); l.w = (u16)f2bf_u(v.w - __uint_as_float((u32)h.w << 16));
    *(ushort4*)&Wh[i4] = h;
    *(ushort4*)&Wl[i4] = l;
}
__global__ __launch_bounds__(256) void cvt_w3(
    const float* __restrict__ w0, const float* __restrict__ w1, const float* __restrict__ w2,
    u16* __restrict__ h0, u16* __restrict__ l0,
    u16* __restrict__ h1, u16* __restrict__ l1,
    u16* __restrict__ h2, u16* __restrict__ l2) {
    int wi = blockIdx.x >> 8;
    int i4 = ((blockIdx.x & 255) * 256 + threadIdx.x) * 4;
    const float* W = (wi == 0) ? w0 : (wi == 1) ? w1 : w2;
    u16* Wh = (wi == 0) ? h0 : (wi == 1) ? h1 : h2;
    u16* Wl = (wi == 0) ? l0 : (wi == 1) ? l1 : l2;
    cvt_one(W, Wh, Wl, i4);
}
__global__ __launch_bounds__(256) void cvt_w(const float* __restrict__ W,
                                             u16* __restrict__ Wh, u16* __restrict__ Wl) {
    int i4 = (blockIdx.x * 256 + threadIdx.x) * 4;
    cvt_one(W, Wh, Wl, i4);
}

// ---------------------------------------------------------------------------
// 4) Split-bf16 MFMA GEMM (R7 structure: 3D grid, single buffer, K=512).
//    D[m][n] = sum_k A[m][k] * B[n][k]; 128x128 tile, BK=32, 4 waves.
//    grid = (n-blocks[, sel], m-blocks, batch).
//    APK: A rows are packed u32 (hi|lo<<16), per-batch stride sAb.
//    !APK: A is shared split bf16 arrays A1h/A1l (u16, k-contig).
//    QKF: blockIdx.x = {sel(2) x nb(2)}; sel picks (A1,Yv) vs (A2,Yv2).
//    rowidx: B row n gathered as rowidx[b*KK+n].
//    EPI 0: Y packed u32 [n][c].  EPI 1: Y f32 [c][n] + residual (ld=NN).
//    EPI 2: Y f32 [m][n]*scale clipped to +-80 (ld=ldy).
// ---------------------------------------------------------------------------
template<int EPI, bool QKF, bool APK>
__global__ __launch_bounds__(256) void mfma_gemm(
    const void* A1h, const void* A1l,
    const void* A2h, const void* A2l,
    long sAb,
    const u32* __restrict__ Bpk, long sBb,
    const int* __restrict__ rowidx,
    const float* __restrict__ Xres,
    void* Yv, void* Yv2, long sYb, int ldy, float scalev)
{
    __shared__ u32 smem[8192];             // 32 KB
    u16* sAh  = (u16*)smem;                // 8 KB  (!APK)
    u16* sAl  = (u16*)(smem + 2048);       // 8 KB  (!APK)
    u32* sA32 = smem;                      // 16 KB (APK)
    u32* sB   = smem + 4096;               // 16 KB
    const int gx  = blockIdx.x;
    const int sel = QKF ? (gx >> 1) : 0;
    const int n0  = QKF ? ((gx & 1) * 128) : (gx * 128);
    const int c0  = blockIdx.y * 128;
    const int b   = blockIdx.z;
    const int t = threadIdx.x;
    const int wid = t >> 6, lane = t & 63;
    const int mw = (wid >> 1) * 64, nw = (wid & 1) * 64;
    const int lm = lane & 15, lk = lane >> 4;
    const u32* Bb = Bpk + (size_t)b * sBb;
    const u16* Ah = (const u16*)((QKF && sel) ? A2h : A1h);
    const u16* Al = (const u16*)((QKF && sel) ? A2l : A1l);
    const u32* Apk = (const u32*)A1h + (size_t)b * sAb;

    // hoist the 4 B-row base offsets (gathered for q/k path)
    size_t brow[4];
    #pragma unroll
    for (int i = 0; i < 4; ++i) {
        int r = (t >> 3) + 32 * i;
        int gr = rowidx ? rowidx[b * KK + n0 + r] : (n0 + r);
        brow[i] = (size_t)gr * CC;
    }

    f32x4 acc[4][4] = {};

    for (int k0 = 0; k0 < 512; k0 += 32) {
        if constexpr (!APK) {
            #pragma unroll
            for (int i = 0; i < 2; ++i) {      // A tiles: 2x 8KB
                int e = t + 256 * i, r = e >> 2, ch = e & 3;
                int gch = ch ^ (r & 3);        // pre-swizzled source chunk
                gl16(&Ah[(size_t)(c0 + r) * 512 + k0 + gch * 8], &sAh[e * 8]);
                gl16(&Al[(size_t)(c0 + r) * 512 + k0 + gch * 8], &sAl[e * 8]);
            }
        } else {
            #pragma unroll
            for (int i = 0; i < 4; ++i) {      // A tile: 16KB packed
                int e = t + 256 * i, r = e >> 3, ch = e & 7;
                int gch = ch ^ (r & 7);
                gl16(&Apk[(size_t)(c0 + r) * 512 + k0 + gch * 4], &sA32[e * 4]);
            }
        }
        #pragma unroll
        for (int i = 0; i < 4; ++i) {          // B tile: 16KB
            int e = t + 256 * i, ch = e & 7;
            int r = (t >> 3) + 32 * i;
            int gch = ch ^ (r & 7);
            gl16(&Bb[brow[i] + k0 + gch * 4], &sB[e * 4]);
        }
        __syncthreads();

        short8 ah[4], al[4], bh[4], bl[4];
        #pragma unroll
        for (int i = 0; i < 4; ++i) {
            int m = mw + 16 * i + lm;
            if constexpr (!APK) {
                int ach = lk ^ (m & 3);
                ah[i] = *(const short8*)&sAh[m * 32 + ach * 8];
                al[i] = *(const short8*)&sAl[m * 32 + ach * 8];
            } else {
                const u32* pa = &sA32[m * 32];
                int ca = (2 * lk) ^ (m & 7);
                int cb = (2 * lk + 1) ^ (m & 7);
                uint4 u0 = *(const uint4*)&pa[ca * 4];
                uint4 u1 = *(const uint4*)&pa[cb * 4];
                union { u32 u[4]; short8 s; } H, L;
                H.u[0] = __builtin_amdgcn_perm(u0.y, u0.x, 0x05040100u);
                H.u[1] = __builtin_amdgcn_perm(u0.w, u0.z, 0x05040100u);
                H.u[2] = __builtin_amdgcn_perm(u1.y, u1.x, 0x05040100u);
                H.u[3] = __builtin_amdgcn_perm(u1.w, u1.z, 0x05040100u);
                L.u[0] = __builtin_amdgcn_perm(u0.y, u0.x, 0x07060302u);
                L.u[1] = __builtin_amdgcn_perm(u0.w, u0.z, 0x07060302u);
                L.u[2] = __builtin_amdgcn_perm(u1.y, u1.x, 0x07060302u);
                L.u[3] = __builtin_amdgcn_perm(u1.w, u1.z, 0x07060302u);
                ah[i] = H.s; al[i] = L.s;
            }
        }
        #pragma unroll
        for (int j = 0; j < 4; ++j) {
            int n = nw + 16 * j + lm;
            const u32* prow = &sB[n * 32];
            int ca = (2 * lk) ^ (n & 7);
            int cb = (2 * lk + 1) ^ (n & 7);
            uint4 u0 = *(const uint4*)&prow[ca * 4];   // k 0..3 (hi|lo packed)
            uint4 u1 = *(const uint4*)&prow[cb * 4];   // k 4..7
            union { u32 u[4]; short8 s; } H, L;
            H.u[0] = __builtin_amdgcn_perm(u0.y, u0.x, 0x05040100u);
            H.u[1] = __builtin_amdgcn_perm(u0.w, u0.z, 0x05040100u);
            H.u[2] = __builtin_amdgcn_perm(u1.y, u1.x, 0x05040100u);
            H.u[3] = __builtin_amdgcn_perm(u1.w, u1.z, 0x05040100u);
            L.u[0] = __builtin_amdgcn_perm(u0.y, u0.x, 0x07060302u);
            L.u[1] = __builtin_amdgcn_perm(u0.w, u0.z, 0x07060302u);
            L.u[2] = __builtin_amdgcn_perm(u1.y, u1.x, 0x07060302u);
            L.u[3] = __builtin_amdgcn_perm(u1.w, u1.z, 0x07060302u);
            bh[j] = H.s; bl[j] = L.s;
        }
        #pragma unroll
        for (int i = 0; i < 4; ++i)
            #pragma unroll
            for (int j = 0; j < 4; ++j) {
                acc[i][j] = __builtin_amdgcn_mfma_f32_16x16x32_bf16(ah[i], bh[j], acc[i][j], 0, 0, 0);
                acc[i][j] = __builtin_amdgcn_mfma_f32_16x16x32_bf16(ah[i], bl[j], acc[i][j], 0, 0, 0);
                acc[i][j] = __builtin_amdgcn_mfma_f32_16x16x32_bf16(al[i], bh[j], acc[i][j], 0, 0, 0);
            }
        __syncthreads();
    }

    if (EPI == 0) {
        u32* Y = (u32*)((QKF && sel) ? Yv2 : Yv) + (size_t)b * sYb;
        #pragma unroll
        for (int i = 0; i < 4; ++i)
            #pragma unroll
            for (int j = 0; j < 4; ++j) {
                uint4 o;
                o.x = packf(acc[i][j][0]);
                o.y = packf(acc[i][j][1]);
                o.z = packf(acc[i][j][2]);
                o.w = packf(acc[i][j][3]);
                *(uint4*)&Y[(size_t)(n0 + nw + 16 * j + lm) * CC + c0 + mw + 16 * i + 4 * lk] = o;
            }
    } else if (EPI == 1) {
        float* Y = (float*)Yv + (size_t)b * sYb;
        const float* Xb = Xres + (size_t)b * sYb;
        #pragma unroll
        for (int i = 0; i < 4; ++i)
            #pragma unroll
            for (int r = 0; r < 4; ++r) {
                size_t roff = (size_t)(c0 + mw + 16 * i + 4 * lk + r) * NN;
                #pragma unroll
                for (int j = 0; j < 4; ++j) {
                    size_t off = roff + n0 + nw + 16 * j + lm;
                    Y[off] = acc[i][j][r] + Xb[off];
                }
            }
    } else {
        float* Y = (float*)Yv + (size_t)b * sYb;
        #pragma unroll
        for (int i = 0; i < 4; ++i)
            #pragma unroll
            for (int r = 0; r < 4; ++r) {
                size_t roff = (size_t)(c0 + mw + 16 * i + 4 * lk + r) * ldy;
                #pragma unroll
                for (int j = 0; j < 4; ++j) {
                    float v = acc[i][j][r] * scalev;
                    v = fminf(fmaxf(v, -80.f), 80.f);
                    Y[roff + n0 + nw + 16 * j + lm] = v;
                }
            }
    }
}

// ---------------------------------------------------------------------------
// fp32 tiled GEMM (PV only)
// ---------------------------------------------------------------------------
template<bool BT, bool RES, bool SC, bool YT>
__global__ __launch_bounds__(256) void tile_gemm(
    const float* __restrict__ A, long sAb, int lda,
    const float* __restrict__ Bm, long sBb, int ldb,
    const float* __restrict__ R, long sRb,
    float* __restrict__ Y, long sYb, int ldy,
    int Kd, float scalev)
{
    __shared__ float At[16][68];
    __shared__ float Bt[16][68];
    const int b  = blockIdx.z;
    const int n0 = blockIdx.x * 64;
    const int m0 = blockIdx.y * 64;
    const int tid = threadIdx.x;
    const int ti = tid >> 4, tj = tid & 15;
    const int arow = tid >> 2, akk = (tid & 3) << 2;
    const int bkk  = tid >> 4, bjx = (tid & 15) << 2;
    const float* Ab = A  + (size_t)b * sAb;
    const float* Bb = Bm + (size_t)b * sBb;
    float acc[4][4] = {{0.f}};

    for (int k0 = 0; k0 < Kd; k0 += 16) {
        float4 a4 = *(const float4*)&Ab[(size_t)(m0 + arow) * lda + k0 + akk];
        At[akk + 0][arow] = a4.x; At[akk + 1][arow] = a4.y;
        At[akk + 2][arow] = a4.z; At[akk + 3][arow] = a4.w;
        if (BT) {
            float4 b4 = *(const float4*)&Bb[(size_t)(n0 + arow) * ldb + k0 + akk];
            Bt[akk + 0][arow] = b4.x; Bt[akk + 1][arow] = b4.y;
            Bt[akk + 2][arow] = b4.z; Bt[akk + 3][arow] = b4.w;
        } else {
            *(float4*)&Bt[bkk][bjx] = *(const float4*)&Bb[(size_t)(k0 + bkk) * ldb + n0 + bjx];
        }
        __syncthreads();
        #pragma unroll
        for (int kk = 0; kk < 16; ++kk) {
            const float4 av = *(const float4*)&At[kk][ti * 4];
            const float4 bv = *(const float4*)&Bt[kk][tj * 4];
            const float ar[4] = {av.x, av.y, av.z, av.w};
            const float br[4] = {bv.x, bv.y, bv.z, bv.w};
            #pragma unroll
            for (int r = 0; r < 4; ++r)
                #pragma unroll
                for (int c = 0; c < 4; ++c)
                    acc[r][c] += ar[r] * br[c];
        }
        __syncthreads();
    }

    float* Yb = Y + (size_t)b * sYb;
    if (YT) {
        #pragma unroll
        for (int c = 0; c < 4; ++c) {
            float4 o4 = make_float4(acc[0][c], acc[1][c], acc[2][c], acc[3][c]);
            *(float4*)&Yb[(size_t)(n0 + tj * 4 + c) * ldy + (m0 + ti * 4)] = o4;
        }
    } else {
        const float* Rb = RES ? (R + (size_t)b * sRb) : nullptr;
        #pragma unroll
        for (int r = 0; r < 4; ++r) {
            float4 o4 = make_float4(acc[r][0], acc[r][1], acc[r][2], acc[r][3]);
            if (SC) {
                o4.x = fminf(fmaxf(o4.x * scalev, -80.f), 80.f);
                o4.y = fminf(fmaxf(o4.y * scalev, -80.f), 80.f);
                o4.z = fminf(fmaxf(o4.z * scalev, -80.f), 80.f);
                o4.w = fminf(fmaxf(o4.w * scalev, -80.f), 80.f);
            }
            size_t off = (size_t)(m0 + ti * 4 + r) * ldy + n0 + tj * 4;
            if (RES) {
                float4 r4 = *(const float4*)&Rb[off];
                o4.x += r4.x; o4.y += r4.y; o4.z += r4.z; o4.w += r4.w;
            }
            *(float4*)&Yb[off] = o4;
        }
    }
}

// ---------------------------------------------------------------------------
// LayerNorm packed rows -> packed in-place, fused q+k (row_g>=4096 -> k)
// ---------------------------------------------------------------------------
__global__ __launch_bounds__(256) void ln_rows_packed(u32* __restrict__ Q,
                                                      u32* __restrict__ Kb,
                                                      const float* __restrict__ lnw,
                                                      const float* __restrict__ lnb) {
    const int wave = threadIdx.x >> 6, lane = threadIdx.x & 63;
    const int row_g = blockIdx.x * 4 + wave;
    u32* base = (row_g < BB * KK) ? Q : Kb;
    const int row = row_g & (BB * KK - 1);
    u32* p = base + (size_t)row * CC;
    uint4 ua = *(uint4*)&p[lane * 4];
    uint4 ub = *(uint4*)&p[256 + lane * 4];
    float4 v0 = make_float4(unpackf(ua.x), unpackf(ua.y), unpackf(ua.z), unpackf(ua.w));
    float4 v1 = make_float4(unpackf(ub.x), unpackf(ub.y), unpackf(ub.z), unpackf(ub.w));
    float s  = v0.x + v0.y + v0.z + v0.w + v1.x + v1.y + v1.z + v1.w;
    float s2 = v0.x*v0.x + v0.y*v0.y + v0.z*v0.z + v0.w*v0.w
             + v1.x*v1.x + v1.y*v1.y + v1.z*v1.z + v1.w*v1.w;
    #pragma unroll
    for (int m = 32; m >= 1; m >>= 1) { s += __shfl_xor(s, m); s2 += __shfl_xor(s2, m); }
    const float mean = s * (1.f / 512.f);
    const float var  = s2 * (1.f / 512.f) - mean * mean;
    const float rstd = rsqrtf(var + LNEPS);
    float4 w0 = *(const float4*)&lnw[lane * 4],        b0 = *(const float4*)&lnb[lane * 4];
    float4 w1 = *(const float4*)&lnw[256 + lane * 4],  b1 = *(const float4*)&lnb[256 + lane * 4];
    v0.x = (v0.x - mean) * rstd * w0.x + b0.x;  v0.y = (v0.y - mean) * rstd * w0.y + b0.y;
    v0.z = (v0.z - mean) * rstd * w0.z + b0.z;  v0.w = (v0.w - mean) * rstd * w0.w + b0.w;
    v1.x = (v1.x - mean) * rstd * w1.x + b1.x;  v1.y = (v1.y - mean) * rstd * w1.y + b1.y;
    v1.z = (v1.z - mean) * rstd * w1.z + b1.z;  v1.w = (v1.w - mean) * rstd * w1.w + b1.w;
    ua.x = packf(v0.x); ua.y = packf(v0.y); ua.z = packf(v0.z); ua.w = packf(v0.w);
    ub.x = packf(v1.x); ub.y = packf(v1.y); ub.z = packf(v1.z); ub.w = packf(v1.w);
    *(uint4*)&p[lane * 4] = ua;
    *(uint4*)&p[256 + lane * 4] = ub;
}

// ---------------------------------------------------------------------------
// softmax over rows of S[row][256] in-place (one wave per row)
// ---------------------------------------------------------------------------
__global__ __launch_bounds__(256) void softmax_rows(float* __restrict__ S) {
    const int wave = threadIdx.x >> 6, lane = threadIdx.x & 63;
    const int row = blockIdx.x * 4 + wave;
    float* p = S + (size_t)row * KK;
    float4 v = *(float4*)&p[lane * 4];
    float m = fmaxf(fmaxf(v.x, v.y), fmaxf(v.z, v.w));
    #pragma unroll
    for (int mk = 32; mk >= 1; mk >>= 1) m = fmaxf(m, __shfl_xor(m, mk));
    float4 e = make_float4(expf(v.x - m), expf(v.y - m), expf(v.z - m), expf(v.w - m));
    float s = e.x + e.y + e.z + e.w;
    #pragma unroll
    for (int mk = 32; mk >= 1; mk >>= 1) s += __shfl_xor(s, mk);
    const float inv = 1.f / s;
    e.x *= inv; e.y *= inv; e.z *= inv; e.w *= inv;
    *(float4*)&p[lane * 4] = e;
}

// ---------------------------------------------------------------------------
// gather: vsel[b*K+j][c] f32 = unpack(vbufT[b][idx][c])  (contiguous rows)
// ---------------------------------------------------------------------------
__global__ __launch_bounds__(256) void gather_vsel(const u32* __restrict__ VT,
                                                   const int* __restrict__ idx,
                                                   float* __restrict__ Vsel) {
    const int wave = threadIdx.x >> 6, lane = threadIdx.x & 63;
    const int gj = blockIdx.x * 4 + wave;
    const int b = gj >> 8, j = gj & 255;
    const int n = idx[b * KK + j];
    const u32* vp = VT + ((size_t)b * NN + n) * CC;
    float* op = Vsel + (size_t)gj * CC;
    uint4 ua = *(const uint4*)&vp[lane * 8];
    uint4 ub = *(const uint4*)&vp[lane * 8 + 4];
    float4 fa = make_float4(unpackf(ua.x), unpackf(ua.y), unpackf(ua.z), unpackf(ua.w));
    float4 fb = make_float4(unpackf(ub.x), unpackf(ub.y), unpackf(ub.z), unpackf(ub.w));
    *(float4*)&op[lane * 8] = fa;
    *(float4*)&op[lane * 8 + 4] = fb;
}

// ---------------------------------------------------------------------------
// scatter: vbufT[b][idx[i]][c] = pack(att[b*K+i][c])  (contiguous rows)
// ---------------------------------------------------------------------------
__global__ __launch_bounds__(256) void scatter_att(const float* __restrict__ Att,
                                                   const int* __restrict__ idx,
                                                   u32* __restrict__ VT) {
    const int wave = threadIdx.x >> 6, lane = threadIdx.x & 63;
    const int gi = blockIdx.x * 4 + wave;
    const int b = gi >> 8, i = gi & 255;
    const int n = idx[b * KK + i];
    const float* ap = Att + (size_t)gi * CC;
    u32* vp = VT + ((size_t)b * NN + n) * CC;
    float4 fa = *(const float4*)&ap[lane * 8];
    float4 fb = *(const float4*)&ap[lane * 8 + 4];
    uint4 ua, ub;
    ua.x = packf(fa.x); ua.y = packf(fa.y); ua.z = packf(fa.z); ua.w = packf(fa.w);
    ub.x = packf(fb.x); ub.y = packf(fb.y); ub.z = packf(fb.z); ub.w = packf(fb.w);
    *(uint4*)&vp[lane * 8] = ua;
    *(uint4*)&vp[lane * 8 + 4] = ub;
}

// ---------------------------------------------------------------------------
extern "C" void kernel_launch(void* const* d_in, const int* in_sizes, int n_in,
                              void* d_out, int out_size, void* d_ws, size_t ws_size,
                              hipStream_t stream) {
    const float* x   = (const float*)d_in[0];
    const float* wq  = (const float*)d_in[1];
    const float* wk  = (const float*)d_in[2];
    const float* wv  = (const float*)d_in[3];
    const float* wo  = (const float*)d_in[4];
    const float* lnw = (const float*)d_in[5];
    const float* lnb = (const float*)d_in[6];
    float* out = (float*)d_out;

    // workspace layout (bytes); total 113,262,592 (= proven usage)
    char* w = (char*)d_ws;
    int*    idx   = (int*)w;                            // 16 KB
    double* impd  = (double*)(w + 16384);               // 295 KB (in 8MB att region)
    float*  att   = (float*)(w + 16384);
    u32*    qbufP = (u32*)(w + 8404992);                // 8 MB (WvH/L first, then qbuf)
    u32*    kbufP = (u32*)(w + 16793600);               // 8 MB (kbuf, then WoH/L)
    float*  S     = (float*)(w + 25182208);             // 4 MB
    float*  vsel  = (float*)(w + 29376512);             // 8 MB (WqH/L,WkH/L first)
    u32*    vbufT = (u32*)(w + 37765120);               // 75.5 MB packed [b][n][c]
    u16* WvH = (u16*)qbufP;  u16* WvL = WvH + 262144;
    u16* WoH = (u16*)kbufP;  u16* WoL = WoH + 262144;
    u16* WqH = (u16*)vsel;   u16* WqL = WqH + 262144;
    u16* WkH = WqH + 524288; u16* WkL = WqH + 786432;
    u32* XT  = (u32*)d_out;                             // x^T packed, scratch in d_out

    const long sXp = (long)NN * CC;                     // packed per-batch stride
    const long sQp = (long)KK * CC;
    const long sQ  = (long)KK * CC;
    const long sS  = (long)KK * KK;

    hipMemsetAsync(impd, 0, (size_t)BB * NN * sizeof(double), stream);
    transpose_imp<<<dim3(NN / 64, CC / 64, BB), dim3(256), 0, stream>>>(x, XT, impd);
    topk_kernel<<<dim3(BB), dim3(1024), 0, stream>>>(impd, idx);

    cvt_w3<<<dim3(768), dim3(256), 0, stream>>>(wv, wq, wk, WvH, WvL, WqH, WqL, WkH, WkL);

    // V-projection: vbufT[n][c] = pack( (wv @ x)^T )
    mfma_gemm<0, false, false><<<dim3(18, 4, BB), dim3(256), 0, stream>>>(
        WvH, WvL, nullptr, nullptr, 0, XT, sXp, nullptr, nullptr,
        (void*)vbufT, nullptr, sXp, 0, 1.f);

    // fused q+k projections on selected columns -> packed [k][c]
    mfma_gemm<0, true, false><<<dim3(4, 4, BB), dim3(256), 0, stream>>>(
        WqH, WqL, WkH, WkL, 0, XT, sXp, idx, nullptr,
        (void*)qbufP, (void*)kbufP, sQp, 0, 1.f);

    // fused layernorm q+k, packed in-place
    ln_rows_packed<<<dim3(2 * BB * KK / 4), dim3(256), 0, stream>>>(qbufP, kbufP, lnw, lnb);

    // attention logits S = clip(scale * Qn Kn^T) via packed-A MFMA
    mfma_gemm<2, false, true><<<dim3(2, 2, BB), dim3(256), 0, stream>>>(
        qbufP, nullptr, nullptr, nullptr, sQp, kbufP, sQp, nullptr, nullptr,
        (void*)S, nullptr, sS, KK, SCALE);
    softmax_rows<<<dim3(BB * KK / 4), dim3(256), 0, stream>>>(S);

    gather_vsel<<<dim3(BB * KK / 4), dim3(256), 0, stream>>>(vbufT, idx, vsel);
    // attended = P @ vsel -> att[b][i][c]
    tile_gemm<false,false,false,false><<<dim3(CC/64, KK/64, BB), dim3(256), 0, stream>>>(
        S, sS, KK, vsel, sQ, CC, nullptr, 0, att, sQ, CC, KK, 1.f);
    scatter_att<<<dim3(BB * KK / 4), dim3(256), 0, stream>>>(att, idx, vbufT);

    cvt_w<<<dim3(256), dim3(256), 0, stream>>>(wo, WoH, WoL);
    // O-projection: out[c][n] = x + wo @ vbuf
    mfma_gemm<1, false, false><<<dim3(18, 4, BB), dim3(256), 0, stream>>>(
        WoH, WoL, nullptr, nullptr, 0, vbufT, sXp, nullptr, x,
        (void*)out, nullptr, (long)CC * NN, 0, 1.f);
}